// Round 11
// baseline (358.867 us; speedup 1.0000x reference)
//
#include <hip/hip_runtime.h>
#include <math.h>

#define SEQ 2048
#define DMODEL 1024
#define NHEADS 16
#define HDIM 64
#define BATCH 2
#define MROWS (BATCH*SEQ)    // 4096
#define BHTOT (BATCH*NHEADS) // 32
#define NKT (SEQ/64)         // 32 k-tiles per head

typedef __attribute__((ext_vector_type(8))) short bf16x8_t;
typedef __attribute__((ext_vector_type(4))) float f32x4_t;
typedef unsigned short u16;

__device__ __forceinline__ u16 f2bf(float x) {
    unsigned int u = __float_as_uint(x);
    return (u16)((u + 0x7FFFu + ((u >> 16) & 1u)) >> 16);
}
__device__ __forceinline__ float bf2f(u16 h) {
    return __uint_as_float(((unsigned int)h) << 16);
}
// XOR swizzle (T2 / m201 pattern): permute 16B slots within a 128B row
__device__ __forceinline__ int swz(int row, int colbyte) {
    return colbyte ^ ((row & 7) << 4);
}

// ---------------------------------------------------------------------------
// Elementwise split: x -> (hi, lo) bf16
// ---------------------------------------------------------------------------
__global__ void split_bf16(const float* __restrict__ in,
                           u16* __restrict__ hi, u16* __restrict__ lo, int n4) {
    int idx = blockIdx.x * blockDim.x + threadIdx.x;
    int stride = gridDim.x * blockDim.x;
    for (int i = idx; i < n4; i += stride) {
        float4 v = ((const float4*)in)[i];
        ushort4 h, l;
        h.x = f2bf(v.x); l.x = f2bf(v.x - bf2f(h.x));
        h.y = f2bf(v.y); l.y = f2bf(v.y - bf2f(h.y));
        h.z = f2bf(v.z); l.z = f2bf(v.z - bf2f(h.z));
        h.w = f2bf(v.w); l.w = f2bf(v.w - bf2f(h.w));
        ((ushort4*)hi)[i] = h;
        ((ushort4*)lo)[i] = l;
    }
}

// ---------------------------------------------------------------------------
// 3-term split-bf16 MFMA GEMM: C = (A @ W^T + bias) * oscale
// MODE 0: fp32 C[m*1024+n]
// MODE 2: bf16 hi/lo, V-transposed head layout [bh][64 d][2048 s]
// MODE 3: bf16 hi/lo, head layout [bh][2048 s][64 d]
// ---------------------------------------------------------------------------
template<int MODE>
__global__ __launch_bounds__(256)
void gemm_bf16_3t(const u16* __restrict__ Ahi, const u16* __restrict__ Alo,
                  const u16* __restrict__ Whi, const u16* __restrict__ Wlo,
                  const float* __restrict__ bias, float oscale,
                  float* __restrict__ C, u16* __restrict__ Ch, u16* __restrict__ Cl) {
    const int K = 1024, N = 1024;
    __shared__ u16 As_h[128 * 40];
    __shared__ u16 As_l[128 * 40];
    __shared__ u16 Ws_h[128 * 40];
    __shared__ u16 Ws_l[128 * 40];

    const int tid = threadIdx.x;
    const int lane = tid & 63, w = tid >> 6;
    const int wr = w >> 1, wc = w & 1;
    const int m0 = blockIdx.y * 128, n0 = blockIdx.x * 128;
    const int rb = lane & 15, ko = (lane >> 4) * 8;

    f32x4_t acc[4][4];
    #pragma unroll
    for (int i = 0; i < 4; ++i)
        #pragma unroll
        for (int j = 0; j < 4; ++j)
            acc[i][j] = (f32x4_t){0.f, 0.f, 0.f, 0.f};

    for (int k0 = 0; k0 < K; k0 += 32) {
        #pragma unroll
        for (int s = 0; s < 2; ++s) {
            int c = tid + s * 256;
            int r = c >> 2, q = c & 3;
            size_t ga = (size_t)(m0 + r) * K + k0 + q * 8;
            size_t gw = (size_t)(n0 + r) * K + k0 + q * 8;
            int la = r * 40 + q * 8;
            *(uint4*)&As_h[la] = *(const uint4*)&Ahi[ga];
            *(uint4*)&As_l[la] = *(const uint4*)&Alo[ga];
            *(uint4*)&Ws_h[la] = *(const uint4*)&Whi[gw];
            *(uint4*)&Ws_l[la] = *(const uint4*)&Wlo[gw];
        }
        __syncthreads();

        bf16x8_t ah[4], al[4];
        #pragma unroll
        for (int i = 0; i < 4; ++i) {
            int ra = wr * 64 + i * 16 + rb;
            ah[i] = *(const bf16x8_t*)&As_h[ra * 40 + ko];
            al[i] = *(const bf16x8_t*)&As_l[ra * 40 + ko];
        }
        #pragma unroll
        for (int j = 0; j < 4; ++j) {
            int rw = wc * 64 + j * 16 + rb;
            bf16x8_t wh = *(const bf16x8_t*)&Ws_h[rw * 40 + ko];
            bf16x8_t wl = *(const bf16x8_t*)&Ws_l[rw * 40 + ko];
            #pragma unroll
            for (int i = 0; i < 4; ++i) {
                acc[i][j] = __builtin_amdgcn_mfma_f32_16x16x32_bf16(ah[i], wh, acc[i][j], 0, 0, 0);
                acc[i][j] = __builtin_amdgcn_mfma_f32_16x16x32_bf16(ah[i], wl, acc[i][j], 0, 0, 0);
                acc[i][j] = __builtin_amdgcn_mfma_f32_16x16x32_bf16(al[i], wh, acc[i][j], 0, 0, 0);
            }
        }
        __syncthreads();
    }

    if (MODE == 2) {
        #pragma unroll
        for (int i = 0; i < 4; ++i)
            #pragma unroll
            for (int j = 0; j < 4; ++j) {
                int mb = m0 + wr * 64 + i * 16 + (lane >> 4) * 4;
                int n = n0 + wc * 64 + j * 16 + rb;
                int bb = mb >> 11, s0 = mb & (SEQ - 1);
                int hh = n >> 6, dd = n & 63;
                size_t idx = (((size_t)(bb * 16 + hh) * 64) + dd) * SEQ + s0;
                float bn = bias[n];
                ushort4 h4, l4;
                float v0 = (acc[i][j][0] + bn) * oscale;
                float v1 = (acc[i][j][1] + bn) * oscale;
                float v2 = (acc[i][j][2] + bn) * oscale;
                float v3 = (acc[i][j][3] + bn) * oscale;
                h4.x = f2bf(v0); l4.x = f2bf(v0 - bf2f(h4.x));
                h4.y = f2bf(v1); l4.y = f2bf(v1 - bf2f(h4.y));
                h4.z = f2bf(v2); l4.z = f2bf(v2 - bf2f(h4.z));
                h4.w = f2bf(v3); l4.w = f2bf(v3 - bf2f(h4.w));
                *(ushort4*)&Ch[idx] = h4;
                *(ushort4*)&Cl[idx] = l4;
            }
    } else {
        #pragma unroll
        for (int i = 0; i < 4; ++i)
            #pragma unroll
            for (int j = 0; j < 4; ++j)
                #pragma unroll
                for (int r = 0; r < 4; ++r) {
                    int m = m0 + wr * 64 + i * 16 + (lane >> 4) * 4 + r;
                    int n = n0 + wc * 64 + j * 16 + rb;
                    float v = (acc[i][j][r] + bias[n]) * oscale;
                    if (MODE == 0) {
                        C[(size_t)m * N + n] = v;
                    } else { // MODE 3
                        int bb = m >> 11, s = m & (SEQ - 1);
                        int hh = n >> 6, dd = n & 63;
                        size_t idx = (((size_t)(bb * 16 + hh) * SEQ) + s) * 64 + dd;
                        u16 t = f2bf(v);
                        Ch[idx] = t;
                        Cl[idx] = f2bf(v - bf2f(t));
                    }
                }
    }
}

// ---------------------------------------------------------------------------
// Per-tile V column sums from vT hi/lo: cs[bh][kt][d]
// ---------------------------------------------------------------------------
__global__ void vcolsum(const u16* __restrict__ vth, const u16* __restrict__ vtl,
                        float* __restrict__ cs) {
    int kt = blockIdx.x, bh = blockIdx.y, d = threadIdx.x; // 64 threads
    const u16* ph = vth + ((size_t)bh * 64 + d) * SEQ + kt * 64;
    const u16* pl = vtl + ((size_t)bh * 64 + d) * SEQ + kt * 64;
    float s = 0.f;
    #pragma unroll 16
    for (int j = 0; j < 64; ++j) s += bf2f(ph[j]) + bf2f(pl[j]);
    cs[((size_t)bh * NKT + kt) * 64 + d] = s;
}

// suffix scan: suf[bh][kt][d] = sum_{t>=kt} cs[bh][t][d]
__global__ void suffix_scan(const float* __restrict__ cs, float* __restrict__ suf) {
    int bh = blockIdx.x, d = threadIdx.x;
    float acc = 0.f;
    for (int kt = NKT - 1; kt >= 0; --kt) {
        acc += cs[((size_t)bh * NKT + kt) * 64 + d];
        suf[((size_t)bh * NKT + kt) * 64 + d] = acc;
    }
}

// ---------------------------------------------------------------------------
// MFMA flash attention, split-KV. Block = 4 waves x 32 q-rows (stripe = 128).
// Work decode per bh (24 items): wi<8 -> single-block stripe qi'=wi (<=16 kv
// tiles, finalize in-kernel); wi>=8 -> stripe qi'=8+((wi-8)>>1), chunk
// c=(wi-8)&1 (chunk0 = kv tiles 0..15, chunk1 = 16..nt-1), writes f32
// partials (O, m, l) merged by merge_partials.
// ---------------------------------------------------------------------------
__global__ __launch_bounds__(256)
void attn_mfma(const u16* __restrict__ qh_g, const u16* __restrict__ ql_g,
               const u16* __restrict__ kh_g, const u16* __restrict__ kl_g,
               const u16* __restrict__ vth_g, const u16* __restrict__ vtl_g,
               const float* __restrict__ suf,
               u16* __restrict__ ahi, u16* __restrict__ alo,
               float* __restrict__ pO, float* __restrict__ pm,
               float* __restrict__ pl) {
    __shared__ alignas(16) u16 Ks[2][4096];   // K hi/lo; dead region reused for P_lo
    __shared__ alignas(16) u16 Vh[4096], Vl[4096];
    __shared__ alignas(16) u16 Ph[4][2048];   // per-wave P_hi

    const int tid = threadIdx.x;
    const int lane = tid & 63, w = tid >> 6;
    const int rb = lane & 15, g = lane >> 4;

    const int bh = blockIdx.x / 24;
    const int wi = blockIdx.x % 24;
    const bool single = (wi < 8);
    const int qi = single ? wi : 8 + ((wi - 8) >> 1);
    const int chunk = single ? 0 : ((wi - 8) & 1);
    const int b = bh >> 4, h = bh & 15;
    const int qb0 = qi << 7;                  // stripe base row
    const int dt_w = 2 * qi + (w >> 1);       // this wave's diagonal tile
    const int nt_str = 2 * qi + 2;            // stripe's kv-tile count
    const int kt0 = (chunk == 0) ? 0 : 16;
    const int kt1 = single ? nt_str : ((chunk == 0) ? 16 : nt_str);
    const int slot = bh * 16 + (qi - 8) * 2 + chunk;   // valid when !single

    // Q fragments (B-operand): [nf][ks], already scaled by 0.125
    bf16x8_t qfh[2][2], qfl[2][2];
    {
        const u16* qp = qh_g + ((size_t)bh * SEQ + qb0 + w * 32) * 64;
        const u16* qp2 = ql_g + ((size_t)bh * SEQ + qb0 + w * 32) * 64;
        #pragma unroll
        for (int nf = 0; nf < 2; ++nf)
            #pragma unroll
            for (int ks = 0; ks < 2; ++ks) {
                int m = nf * 16 + rb;
                qfh[nf][ks] = *(const bf16x8_t*)(qp + m * 64 + ks * 32 + g * 8);
                qfl[nf][ks] = *(const bf16x8_t*)(qp2 + m * 64 + ks * 32 + g * 8);
            }
    }

    f32x4_t o[4][2];
    #pragma unroll
    for (int mf = 0; mf < 4; ++mf)
        #pragma unroll
        for (int nf = 0; nf < 2; ++nf)
            o[mf][nf] = (f32x4_t){0.f, 0.f, 0.f, 0.f};
    float mrow[2] = {-1e30f, -1e30f}, lrow[2] = {0.f, 0.f};

    const u16* khb = kh_g + (size_t)bh * SEQ * 64;
    const u16* klb = kl_g + (size_t)bh * SEQ * 64;
    const u16* vhb = vth_g + (size_t)bh * 64 * SEQ;
    const u16* vlb = vtl_g + (size_t)bh * 64 * SEQ;
    u16* phw = Ph[w];
    u16* plw = &Ks[0][0] + w * 2048;          // 4KB slice of the dead K region

    for (int kt = kt0; kt < kt1; ++kt) {
        if (kt != kt0) __syncthreads();   // C: prior P/V reads done before restage
        #pragma unroll
        for (int s = 0; s < 2; ++s) {
            int gg = tid + s * 256;
            int row = gg >> 3, dg = gg & 7;
            int off = row * 128 + swz(row, dg * 16);
            *(uint4*)((char*)Ks[0] + off) = *(const uint4*)(khb + (size_t)(kt * 64 + row) * 64 + dg * 8);
            *(uint4*)((char*)Ks[1] + off) = *(const uint4*)(klb + (size_t)(kt * 64 + row) * 64 + dg * 8);
            *(uint4*)((char*)Vh + off) = *(const uint4*)(vhb + (size_t)row * SEQ + kt * 64 + dg * 8);
            *(uint4*)((char*)Vl + off) = *(const uint4*)(vlb + (size_t)row * SEQ + kt * 64 + dg * 8);
        }
        __syncthreads();                  // A: staging visible
        const bool act = (kt <= dt_w);

        f32x4_t st[4][2];
        if (act) {
            #pragma unroll
            for (int jf = 0; jf < 4; ++jf)
                #pragma unroll
                for (int nf = 0; nf < 2; ++nf)
                    st[jf][nf] = (f32x4_t){0.f, 0.f, 0.f, 0.f};
            #pragma unroll
            for (int ks = 0; ks < 2; ++ks)
                #pragma unroll
                for (int jf = 0; jf < 4; ++jf) {
                    int row = jf * 16 + rb;
                    int off = row * 128 + swz(row, ks * 64 + g * 16);
                    bf16x8_t kh8 = *(const bf16x8_t*)((char*)Ks[0] + off);
                    bf16x8_t kl8 = *(const bf16x8_t*)((char*)Ks[1] + off);
                    #pragma unroll
                    for (int nf = 0; nf < 2; ++nf) {
                        st[jf][nf] = __builtin_amdgcn_mfma_f32_16x16x32_bf16(kh8, qfh[nf][ks], st[jf][nf], 0, 0, 0);
                        st[jf][nf] = __builtin_amdgcn_mfma_f32_16x16x32_bf16(kh8, qfl[nf][ks], st[jf][nf], 0, 0, 0);
                        st[jf][nf] = __builtin_amdgcn_mfma_f32_16x16x32_bf16(kl8, qfh[nf][ks], st[jf][nf], 0, 0, 0);
                    }
                }

            if (kt == dt_w) {
                int mb = ((w & 1) << 5) + rb;
                #pragma unroll
                for (int jf = 0; jf < 4; ++jf)
                    #pragma unroll
                    for (int nf = 0; nf < 2; ++nf) {
                        int mm = mb + nf * 16;
                        int jb = jf * 16 + g * 4;
                        #pragma unroll
                        for (int r = 0; r < 4; ++r)
                            if (jb + r > mm) st[jf][nf][r] = -1e-9f;
                    }
            }

            float alpha[2];
            #pragma unroll
            for (int nf = 0; nf < 2; ++nf) {
                f32x4_t m4;
                #pragma unroll
                for (int r = 0; r < 4; ++r)
                    m4[r] = fmaxf(fmaxf(st[0][nf][r], st[1][nf][r]),
                                  fmaxf(st[2][nf][r], st[3][nf][r]));
                float mx = fmaxf(fmaxf(m4[0], m4[1]), fmaxf(m4[2], m4[3]));
                mx = fmaxf(mx, __shfl_xor(mx, 16));
                mx = fmaxf(mx, __shfl_xor(mx, 32));
                float nm = fmaxf(mrow[nf], mx);
                alpha[nf] = __expf(mrow[nf] - nm);
                mrow[nf] = nm;
            }
            float rsum[2] = {0.f, 0.f};
            #pragma unroll
            for (int jf = 0; jf < 4; ++jf)
                #pragma unroll
                for (int nf = 0; nf < 2; ++nf)
                    #pragma unroll
                    for (int r = 0; r < 4; ++r) {
                        float p = __expf(st[jf][nf][r] - mrow[nf]);
                        st[jf][nf][r] = p;
                        rsum[nf] += p;
                    }
            #pragma unroll
            for (int nf = 0; nf < 2; ++nf) {
                rsum[nf] += __shfl_xor(rsum[nf], 16);
                rsum[nf] += __shfl_xor(rsum[nf], 32);
                lrow[nf] = lrow[nf] * alpha[nf] + rsum[nf];
            }
            #pragma unroll
            for (int mf = 0; mf < 4; ++mf)
                #pragma unroll
                for (int nf = 0; nf < 2; ++nf)
                    #pragma unroll
                    for (int r = 0; r < 4; ++r)
                        o[mf][nf][r] *= alpha[nf];
        }

        __syncthreads();                  // B: all QK^T reads of K done
        if (act) {
            #pragma unroll
            for (int nf = 0; nf < 2; ++nf)
                #pragma unroll
                for (int jf = 0; jf < 4; ++jf) {
                    int m = nf * 16 + rb;
                    int off = m * 128 + swz(m, jf * 32 + g * 8);
                    ushort4 h4, l4;
                    float p0 = st[jf][nf][0], p1 = st[jf][nf][1];
                    float p2 = st[jf][nf][2], p3 = st[jf][nf][3];
                    h4.x = f2bf(p0); l4.x = f2bf(p0 - bf2f(h4.x));
                    h4.y = f2bf(p1); l4.y = f2bf(p1 - bf2f(h4.y));
                    h4.z = f2bf(p2); l4.z = f2bf(p2 - bf2f(h4.z));
                    h4.w = f2bf(p3); l4.w = f2bf(p3 - bf2f(h4.w));
                    *(ushort4*)((char*)phw + off) = h4;
                    *(ushort4*)((char*)plw + off) = l4;
                }

            #pragma unroll
            for (int kk = 0; kk < 2; ++kk) {
                bf16x8_t pbh[2], pbl[2];
                #pragma unroll
                for (int nf = 0; nf < 2; ++nf) {
                    int m = nf * 16 + rb;
                    int off = m * 128 + swz(m, kk * 64 + g * 16);
                    pbh[nf] = *(const bf16x8_t*)((char*)phw + off);
                    pbl[nf] = *(const bf16x8_t*)((char*)plw + off);
                }
                #pragma unroll
                for (int mf = 0; mf < 4; ++mf) {
                    int row = mf * 16 + rb;
                    int off = row * 128 + swz(row, kk * 64 + g * 16);
                    bf16x8_t vh8 = *(const bf16x8_t*)((char*)Vh + off);
                    bf16x8_t vl8 = *(const bf16x8_t*)((char*)Vl + off);
                    #pragma unroll
                    for (int nf = 0; nf < 2; ++nf) {
                        o[mf][nf] = __builtin_amdgcn_mfma_f32_16x16x32_bf16(vh8, pbh[nf], o[mf][nf], 0, 0, 0);
                        o[mf][nf] = __builtin_amdgcn_mfma_f32_16x16x32_bf16(vh8, pbl[nf], o[mf][nf], 0, 0, 0);
                        o[mf][nf] = __builtin_amdgcn_mfma_f32_16x16x32_bf16(vl8, pbh[nf], o[mf][nf], 0, 0, 0);
                    }
                }
            }
        }
    }

    if (!single) {
        // write f32 partials: O [slot][row 128][d 64], m/l [slot][row 128]
        float* po = pO + (size_t)slot * 8192;
        #pragma unroll
        for (int mf = 0; mf < 4; ++mf)
            #pragma unroll
            for (int nf = 0; nf < 2; ++nf) {
                int row = w * 32 + nf * 16 + rb;
                int d = mf * 16 + g * 4;
                *(f32x4_t*)(po + row * 64 + d) = o[mf][nf];
            }
        if (g == 0) {
            #pragma unroll
            for (int nf = 0; nf < 2; ++nf) {
                int row = w * 32 + nf * 16 + rb;
                pm[(size_t)slot * 128 + row] = mrow[nf];
                pl[(size_t)slot * 128 + row] = lrow[nf];
            }
        }
        return;
    }

    // single-block stripes: analytic suffix + finalize
    const int nt_w = dt_w + 1;
    const int nfull = NKT - nt_w;
    if (nfull > 0) {
        float al2[2], ee[2];
        #pragma unroll
        for (int nf = 0; nf < 2; ++nf) {
            float mm = fmaxf(mrow[nf], -1e-9f);
            al2[nf] = __expf(mrow[nf] - mm);
            ee[nf] = __expf(-1e-9f - mm);
            lrow[nf] = lrow[nf] * al2[nf] + ee[nf] * (64.f * (float)nfull);
        }
        const float* sufp = suf + ((size_t)bh * NKT + nt_w) * 64;
        #pragma unroll
        for (int mf = 0; mf < 4; ++mf) {
            float4 sf = *(const float4*)(sufp + mf * 16 + g * 4);
            #pragma unroll
            for (int nf = 0; nf < 2; ++nf) {
                o[mf][nf][0] = o[mf][nf][0] * al2[nf] + ee[nf] * sf.x;
                o[mf][nf][1] = o[mf][nf][1] * al2[nf] + ee[nf] * sf.y;
                o[mf][nf][2] = o[mf][nf][2] * al2[nf] + ee[nf] * sf.z;
                o[mf][nf][3] = o[mf][nf][3] * al2[nf] + ee[nf] * sf.w;
            }
        }
    }

    float inv[2] = {1.f / lrow[0], 1.f / lrow[1]};
    #pragma unroll
    for (int mf = 0; mf < 4; ++mf)
        #pragma unroll
        for (int nf = 0; nf < 2; ++nf) {
            ushort4 h4, l4;
            float v0 = o[mf][nf][0] * inv[nf];
            float v1 = o[mf][nf][1] * inv[nf];
            float v2 = o[mf][nf][2] * inv[nf];
            float v3 = o[mf][nf][3] * inv[nf];
            h4.x = f2bf(v0); l4.x = f2bf(v0 - bf2f(h4.x));
            h4.y = f2bf(v1); l4.y = f2bf(v1 - bf2f(h4.y));
            h4.z = f2bf(v2); l4.z = f2bf(v2 - bf2f(h4.z));
            h4.w = f2bf(v3); l4.w = f2bf(v3 - bf2f(h4.w));
            size_t row = (size_t)b * SEQ + qb0 + w * 32 + nf * 16 + rb;
            size_t col = (size_t)h * 64 + mf * 16 + g * 4;
            *(ushort4*)&ahi[row * DMODEL + col] = h4;
            *(ushort4*)&alo[row * DMODEL + col] = l4;
        }
}

// ---------------------------------------------------------------------------
// Merge the 2 chunks of stripes qi'>=8, apply analytic suffix, normalize,
// emit bf16 hi/lo. One block per stripe (256 stripes), 256 threads.
// ---------------------------------------------------------------------------
__global__ __launch_bounds__(256)
void merge_partials(const float* __restrict__ pO, const float* __restrict__ pm,
                    const float* __restrict__ pl, const float* __restrict__ suf,
                    u16* __restrict__ ahi, u16* __restrict__ alo) {
    const int sid = blockIdx.x;            // 0..255
    const int bh = sid >> 3, j = sid & 7, qi = 8 + j;
    const int b = bh >> 4, h = bh & 15;
    const int slot0 = bh * 16 + j * 2;
    const int t = threadIdx.x;
    const int r = t >> 1, d0 = (t & 1) * 32;

    float m0 = pm[(size_t)slot0 * 128 + r];
    float m1 = pm[(size_t)(slot0 + 1) * 128 + r];
    float l0 = pl[(size_t)slot0 * 128 + r];
    float l1 = pl[(size_t)(slot0 + 1) * 128 + r];
    float m = fmaxf(m0, m1);
    float a0 = __expf(m0 - m), a1 = __expf(m1 - m);
    float l = l0 * a0 + l1 * a1;

    const int nt_w = 2 * qi + (r >> 6) + 1;
    const int nfull = NKT - nt_w;
    float asuf = 1.f, esuf = 0.f;
    if (nfull > 0) {
        float mm = fmaxf(m, -1e-9f);
        asuf = __expf(m - mm);
        esuf = __expf(-1e-9f - mm);
        l = l * asuf + esuf * (64.f * (float)nfull);
    }
    float linv = 1.f / l;

    const float* O0 = pO + (size_t)slot0 * 8192 + r * 64 + d0;
    const float* O1 = O0 + 8192;
    const float* sufp = (nfull > 0) ? (suf + ((size_t)bh * NKT + nt_w) * 64 + d0) : nullptr;
    size_t row = (size_t)b * SEQ + qi * 128 + r;
    u16* oh = ahi + row * DMODEL + h * 64 + d0;
    u16* ol = alo + row * DMODEL + h * 64 + d0;

    #pragma unroll
    for (int q4 = 0; q4 < 8; ++q4) {
        float4 x0 = *(const float4*)(O0 + q4 * 4);
        float4 x1 = *(const float4*)(O1 + q4 * 4);
        float4 y;
        y.x = (x0.x * a0 + x1.x * a1);
        y.y = (x0.y * a0 + x1.y * a1);
        y.z = (x0.z * a0 + x1.z * a1);
        y.w = (x0.w * a0 + x1.w * a1);
        if (nfull > 0) {
            float4 sf = *(const float4*)(sufp + q4 * 4);
            y.x = y.x * asuf + esuf * sf.x;
            y.y = y.y * asuf + esuf * sf.y;
            y.z = y.z * asuf + esuf * sf.z;
            y.w = y.w * asuf + esuf * sf.w;
        }
        y.x *= linv; y.y *= linv; y.z *= linv; y.w *= linv;
        ushort4 h4, l4;
        h4.x = f2bf(y.x); l4.x = f2bf(y.x - bf2f(h4.x));
        h4.y = f2bf(y.y); l4.y = f2bf(y.y - bf2f(h4.y));
        h4.z = f2bf(y.z); l4.z = f2bf(y.z - bf2f(h4.z));
        h4.w = f2bf(y.w); l4.w = f2bf(y.w - bf2f(h4.w));
        *(ushort4*)(oh + q4 * 4) = h4;
        *(ushort4*)(ol + q4 * 4) = l4;
    }
}

// ---------------------------------------------------------------------------
extern "C" void kernel_launch(void* const* d_in, const int* in_sizes, int n_in,
                              void* d_out, int out_size, void* d_ws, size_t ws_size,
                              hipStream_t stream) {
    const float* Q   = (const float*)d_in[0];
    const float* K   = (const float*)d_in[1];
    const float* V   = (const float*)d_in[2];
    // d_in[3] = mask (tril) — structure known, not read
    const float* Wq  = (const float*)d_in[4];
    const float* bq  = (const float*)d_in[5];
    const float* Wk  = (const float*)d_in[6];
    const float* bk  = (const float*)d_in[7];
    const float* Wv  = (const float*)d_in[8];
    const float* bv  = (const float*)d_in[9];
    const float* Wo  = (const float*)d_in[10];
    const float* bo  = (const float*)d_in[11];
    float* out = (float*)d_out;

    float* ws = (float*)d_ws;
    const size_t HEADSZ = (size_t)BHTOT * SEQ * HDIM;   // 4,194,304 elems
    float* cs_ws  = ws;                                  // 65536 f
    float* suf_ws = ws + 65536;                          // 65536 f
    u16* base  = (u16*)(ws + 131072);
    u16* q_hi  = base;
    u16* q_lo  = base + HEADSZ;
    u16* k_hi  = base + 2 * HEADSZ;
    u16* k_lo  = base + 3 * HEADSZ;
    u16* vt_hi = base + 4 * HEADSZ;
    u16* vt_lo = base + 5 * HEADSZ;
    u16* in_hi = base + 6 * HEADSZ;
    u16* in_lo = base + 7 * HEADSZ;
    u16* w_hi  = base + 8 * HEADSZ;
    u16* w_lo  = w_hi + (size_t)DMODEL * DMODEL;
    // split-KV partials: 512 slots x (128x64 O + 128 m + 128 l), ~17.3 MB
    float* pO = (float*)(w_lo + (size_t)DMODEL * DMODEL);
    float* pm = pO + (size_t)512 * 8192;
    float* pl = pm + (size_t)512 * 128;

    const int ACT_N4 = (int)(HEADSZ / 4);
    const int W_N4   = (DMODEL * DMODEL) / 4;
    dim3 sblk(256), sgrid(2048);
    dim3 gblk(256);
    dim3 ggrid(DMODEL / 128, MROWS / 128);               // 8 x 32

    // Q projection (pre-scaled by 1/8 for attention)
    split_bf16<<<sgrid, sblk, 0, stream>>>(Q, in_hi, in_lo, ACT_N4);
    split_bf16<<<dim3(1024), sblk, 0, stream>>>(Wq, w_hi, w_lo, W_N4);
    gemm_bf16_3t<3><<<ggrid, gblk, 0, stream>>>(in_hi, in_lo, w_hi, w_lo, bq, 0.125f,
                                                nullptr, q_hi, q_lo);
    // K projection
    split_bf16<<<sgrid, sblk, 0, stream>>>(K, in_hi, in_lo, ACT_N4);
    split_bf16<<<dim3(1024), sblk, 0, stream>>>(Wk, w_hi, w_lo, W_N4);
    gemm_bf16_3t<3><<<ggrid, gblk, 0, stream>>>(in_hi, in_lo, w_hi, w_lo, bk, 1.f,
                                                nullptr, k_hi, k_lo);
    // V projection (transposed head layout)
    split_bf16<<<sgrid, sblk, 0, stream>>>(V, in_hi, in_lo, ACT_N4);
    split_bf16<<<dim3(1024), sblk, 0, stream>>>(Wv, w_hi, w_lo, W_N4);
    gemm_bf16_3t<2><<<ggrid, gblk, 0, stream>>>(in_hi, in_lo, w_hi, w_lo, bv, 1.f,
                                                nullptr, vt_hi, vt_lo);

    vcolsum<<<dim3(NKT, BHTOT), dim3(64), 0, stream>>>(vt_hi, vt_lo, cs_ws);
    suffix_scan<<<dim3(BHTOT), dim3(64), 0, stream>>>(cs_ws, suf_ws);

    // split-KV MFMA flash attention + merge
    attn_mfma<<<dim3(24 * BHTOT), gblk, 0, stream>>>(q_hi, q_lo, k_hi, k_lo,
                                                     vt_hi, vt_lo, suf_ws,
                                                     in_hi, in_lo, pO, pm, pl);
    merge_partials<<<dim3(256), gblk, 0, stream>>>(pO, pm, pl, suf_ws, in_hi, in_lo);

    // output projection
    split_bf16<<<dim3(1024), sblk, 0, stream>>>(Wo, w_hi, w_lo, W_N4);
    gemm_bf16_3t<0><<<ggrid, gblk, 0, stream>>>(in_hi, in_lo, w_hi, w_lo, bo, 1.f,
                                                out, nullptr, nullptr);
}

// Round 12
// 329.482 us; speedup vs baseline: 1.0892x; 1.0892x over previous
//
#include <hip/hip_runtime.h>
#include <math.h>

#define SEQ 2048
#define DMODEL 1024
#define NHEADS 16
#define HDIM 64
#define BATCH 2
#define MROWS (BATCH*SEQ)    // 4096
#define BHTOT (BATCH*NHEADS) // 32
#define NKT (SEQ/64)         // 32 k-tiles per head

typedef __attribute__((ext_vector_type(8))) short bf16x8_t;
typedef __attribute__((ext_vector_type(4))) float f32x4_t;
typedef unsigned short u16;

__device__ __forceinline__ u16 f2bf(float x) {
    unsigned int u = __float_as_uint(x);
    return (u16)((u + 0x7FFFu + ((u >> 16) & 1u)) >> 16);
}
__device__ __forceinline__ float bf2f(u16 h) {
    return __uint_as_float(((unsigned int)h) << 16);
}
// XOR swizzle (T2 / m201 pattern): permute 16B slots within a 128B row
__device__ __forceinline__ int swz(int row, int colbyte) {
    return colbyte ^ ((row & 7) << 4);
}

// ---------------------------------------------------------------------------
// Elementwise split: x -> (hi, lo) bf16
// ---------------------------------------------------------------------------
__global__ void split_bf16(const float* __restrict__ in,
                           u16* __restrict__ hi, u16* __restrict__ lo, int n4) {
    int idx = blockIdx.x * blockDim.x + threadIdx.x;
    int stride = gridDim.x * blockDim.x;
    for (int i = idx; i < n4; i += stride) {
        float4 v = ((const float4*)in)[i];
        ushort4 h, l;
        h.x = f2bf(v.x); l.x = f2bf(v.x - bf2f(h.x));
        h.y = f2bf(v.y); l.y = f2bf(v.y - bf2f(h.y));
        h.z = f2bf(v.z); l.z = f2bf(v.z - bf2f(h.z));
        h.w = f2bf(v.w); l.w = f2bf(v.w - bf2f(h.w));
        ((ushort4*)hi)[i] = h;
        ((ushort4*)lo)[i] = l;
    }
}

// ---------------------------------------------------------------------------
// 3-term split-bf16 MFMA GEMM: C = (A @ W^T + bias) * oscale
// MODE 0: fp32 C[m*1024+n]
// MODE 2: bf16 hi/lo, V-transposed head layout [bh][64 d][2048 s]
// MODE 3: bf16 hi/lo, head layout [bh][2048 s][64 d]
// ---------------------------------------------------------------------------
template<int MODE>
__global__ __launch_bounds__(256)
void gemm_bf16_3t(const u16* __restrict__ Ahi, const u16* __restrict__ Alo,
                  const u16* __restrict__ Whi, const u16* __restrict__ Wlo,
                  const float* __restrict__ bias, float oscale,
                  float* __restrict__ C, u16* __restrict__ Ch, u16* __restrict__ Cl) {
    const int K = 1024, N = 1024;
    __shared__ u16 As_h[128 * 40];
    __shared__ u16 As_l[128 * 40];
    __shared__ u16 Ws_h[128 * 40];
    __shared__ u16 Ws_l[128 * 40];

    const int tid = threadIdx.x;
    const int lane = tid & 63, w = tid >> 6;
    const int wr = w >> 1, wc = w & 1;
    const int m0 = blockIdx.y * 128, n0 = blockIdx.x * 128;
    const int rb = lane & 15, ko = (lane >> 4) * 8;

    f32x4_t acc[4][4];
    #pragma unroll
    for (int i = 0; i < 4; ++i)
        #pragma unroll
        for (int j = 0; j < 4; ++j)
            acc[i][j] = (f32x4_t){0.f, 0.f, 0.f, 0.f};

    for (int k0 = 0; k0 < K; k0 += 32) {
        #pragma unroll
        for (int s = 0; s < 2; ++s) {
            int c = tid + s * 256;
            int r = c >> 2, q = c & 3;
            size_t ga = (size_t)(m0 + r) * K + k0 + q * 8;
            size_t gw = (size_t)(n0 + r) * K + k0 + q * 8;
            int la = r * 40 + q * 8;
            *(uint4*)&As_h[la] = *(const uint4*)&Ahi[ga];
            *(uint4*)&As_l[la] = *(const uint4*)&Alo[ga];
            *(uint4*)&Ws_h[la] = *(const uint4*)&Whi[gw];
            *(uint4*)&Ws_l[la] = *(const uint4*)&Wlo[gw];
        }
        __syncthreads();

        bf16x8_t ah[4], al[4];
        #pragma unroll
        for (int i = 0; i < 4; ++i) {
            int ra = wr * 64 + i * 16 + rb;
            ah[i] = *(const bf16x8_t*)&As_h[ra * 40 + ko];
            al[i] = *(const bf16x8_t*)&As_l[ra * 40 + ko];
        }
        #pragma unroll
        for (int j = 0; j < 4; ++j) {
            int rw = wc * 64 + j * 16 + rb;
            bf16x8_t wh = *(const bf16x8_t*)&Ws_h[rw * 40 + ko];
            bf16x8_t wl = *(const bf16x8_t*)&Ws_l[rw * 40 + ko];
            #pragma unroll
            for (int i = 0; i < 4; ++i) {
                acc[i][j] = __builtin_amdgcn_mfma_f32_16x16x32_bf16(ah[i], wh, acc[i][j], 0, 0, 0);
                acc[i][j] = __builtin_amdgcn_mfma_f32_16x16x32_bf16(ah[i], wl, acc[i][j], 0, 0, 0);
                acc[i][j] = __builtin_amdgcn_mfma_f32_16x16x32_bf16(al[i], wh, acc[i][j], 0, 0, 0);
            }
        }
        __syncthreads();
    }

    if (MODE == 2) {
        #pragma unroll
        for (int i = 0; i < 4; ++i)
            #pragma unroll
            for (int j = 0; j < 4; ++j) {
                int mb = m0 + wr * 64 + i * 16 + (lane >> 4) * 4;
                int n = n0 + wc * 64 + j * 16 + rb;
                int bb = mb >> 11, s0 = mb & (SEQ - 1);
                int hh = n >> 6, dd = n & 63;
                size_t idx = (((size_t)(bb * 16 + hh) * 64) + dd) * SEQ + s0;
                float bn = bias[n];
                ushort4 h4, l4;
                float v0 = (acc[i][j][0] + bn) * oscale;
                float v1 = (acc[i][j][1] + bn) * oscale;
                float v2 = (acc[i][j][2] + bn) * oscale;
                float v3 = (acc[i][j][3] + bn) * oscale;
                h4.x = f2bf(v0); l4.x = f2bf(v0 - bf2f(h4.x));
                h4.y = f2bf(v1); l4.y = f2bf(v1 - bf2f(h4.y));
                h4.z = f2bf(v2); l4.z = f2bf(v2 - bf2f(h4.z));
                h4.w = f2bf(v3); l4.w = f2bf(v3 - bf2f(h4.w));
                *(ushort4*)&Ch[idx] = h4;
                *(ushort4*)&Cl[idx] = l4;
            }
    } else {
        #pragma unroll
        for (int i = 0; i < 4; ++i)
            #pragma unroll
            for (int j = 0; j < 4; ++j)
                #pragma unroll
                for (int r = 0; r < 4; ++r) {
                    int m = m0 + wr * 64 + i * 16 + (lane >> 4) * 4 + r;
                    int n = n0 + wc * 64 + j * 16 + rb;
                    float v = (acc[i][j][r] + bias[n]) * oscale;
                    if (MODE == 0) {
                        C[(size_t)m * N + n] = v;
                    } else { // MODE 3
                        int bb = m >> 11, s = m & (SEQ - 1);
                        int hh = n >> 6, dd = n & 63;
                        size_t idx = (((size_t)(bb * 16 + hh) * SEQ) + s) * 64 + dd;
                        u16 t = f2bf(v);
                        Ch[idx] = t;
                        Cl[idx] = f2bf(v - bf2f(t));
                    }
                }
    }
}

// ---------------------------------------------------------------------------
// Per-tile V column sums from vT hi/lo: cs[bh][kt][d]
// ---------------------------------------------------------------------------
__global__ void vcolsum(const u16* __restrict__ vth, const u16* __restrict__ vtl,
                        float* __restrict__ cs) {
    int kt = blockIdx.x, bh = blockIdx.y, d = threadIdx.x; // 64 threads
    const u16* ph = vth + ((size_t)bh * 64 + d) * SEQ + kt * 64;
    const u16* pl = vtl + ((size_t)bh * 64 + d) * SEQ + kt * 64;
    float s = 0.f;
    #pragma unroll 16
    for (int j = 0; j < 64; ++j) s += bf2f(ph[j]) + bf2f(pl[j]);
    cs[((size_t)bh * NKT + kt) * 64 + d] = s;
}

// suffix scan: suf[bh][kt][d] = sum_{t>=kt} cs[bh][t][d]
__global__ void suffix_scan(const float* __restrict__ cs, float* __restrict__ suf) {
    int bh = blockIdx.x, d = threadIdx.x;
    float acc = 0.f;
    for (int kt = NKT - 1; kt >= 0; --kt) {
        acc += cs[((size_t)bh * NKT + kt) * 64 + d];
        suf[((size_t)bh * NKT + kt) * 64 + d] = acc;
    }
}

// ---------------------------------------------------------------------------
// MFMA flash attention with T14 async-STAGE: per tile, the 8x16B K/V loads
// for tile kt+1 are issued into registers right after tile kt's ds_write, so
// HBM latency hides under QK^T/softmax/PV. Block = 4 waves x 32 q-rows.
// S^T = mfma(K, Q); P_hi in dedicated LDS, P_lo aliases the dead K region.
// LDS 48 KB -> 3 blocks/CU. Fully-masked suffix handled analytically.
// ---------------------------------------------------------------------------
__global__ __launch_bounds__(256)
void attn_mfma(const u16* __restrict__ qh_g, const u16* __restrict__ ql_g,
               const u16* __restrict__ kh_g, const u16* __restrict__ kl_g,
               const u16* __restrict__ vth_g, const u16* __restrict__ vtl_g,
               const float* __restrict__ suf,
               u16* __restrict__ ahi, u16* __restrict__ alo) {
    __shared__ alignas(16) u16 Ks[2][4096];   // K hi/lo; dead region reused for P_lo
    __shared__ alignas(16) u16 Vh[4096], Vl[4096];
    __shared__ alignas(16) u16 Ph[4][2048];   // per-wave P_hi

    const int tid = threadIdx.x;
    const int lane = tid & 63, w = tid >> 6;
    const int rb = lane & 15, g = lane >> 4;
    const int qi = blockIdx.x >> 5;          // 0..15
    const int bh = blockIdx.x & 31;
    const int b = bh >> 4, h = bh & 15;
    const int qb0 = (15 - qi) << 7;          // heavy blocks first
    const int dt_w = (qb0 >> 6) + (w >> 1);  // this wave's diagonal tile
    const int nt_blk = (qb0 >> 6) + 2;

    // Q fragments (B-operand): [nf][ks], already scaled by 0.125
    bf16x8_t qfh[2][2], qfl[2][2];
    {
        const u16* qp = qh_g + ((size_t)bh * SEQ + qb0 + w * 32) * 64;
        const u16* qp2 = ql_g + ((size_t)bh * SEQ + qb0 + w * 32) * 64;
        #pragma unroll
        for (int nf = 0; nf < 2; ++nf)
            #pragma unroll
            for (int ks = 0; ks < 2; ++ks) {
                int m = nf * 16 + rb;
                qfh[nf][ks] = *(const bf16x8_t*)(qp + m * 64 + ks * 32 + g * 8);
                qfl[nf][ks] = *(const bf16x8_t*)(qp2 + m * 64 + ks * 32 + g * 8);
            }
    }

    f32x4_t o[4][2];
    #pragma unroll
    for (int mf = 0; mf < 4; ++mf)
        #pragma unroll
        for (int nf = 0; nf < 2; ++nf)
            o[mf][nf] = (f32x4_t){0.f, 0.f, 0.f, 0.f};
    float mrow[2] = {-1e30f, -1e30f}, lrow[2] = {0.f, 0.f};

    const u16* khb = kh_g + (size_t)bh * SEQ * 64;
    const u16* klb = kl_g + (size_t)bh * SEQ * 64;
    const u16* vhb = vth_g + (size_t)bh * 64 * SEQ;
    const u16* vlb = vtl_g + (size_t)bh * 64 * SEQ;
    u16* phw = Ph[w];
    u16* plw = &Ks[0][0] + w * 2048;         // 4KB slice of the dead K region

    // per-thread staging geometry (2 rows of 8 halves per buffer)
    const int row0 = tid >> 3, dg = tid & 7;         // s=0: rows 0..31
    const int row1 = row0 + 32;                      // s=1: rows 32..63
    const int offs0 = row0 * 128 + swz(row0, dg * 16);
    const int offs1 = row1 * 128 + swz(row1, dg * 16);

    // prefetch registers (T14): K hi/lo + V hi/lo for the next tile
    uint4 rKh0, rKh1, rKl0, rKl1, rVh0, rVh1, rVl0, rVl1;
    {   // prologue: issue tile 0
        const u16* kp0 = khb + (size_t)row0 * 64 + dg * 8;
        const u16* kp1 = khb + (size_t)row1 * 64 + dg * 8;
        const u16* lp0 = klb + (size_t)row0 * 64 + dg * 8;
        const u16* lp1 = klb + (size_t)row1 * 64 + dg * 8;
        const u16* vp0 = vhb + (size_t)row0 * SEQ + dg * 8;
        const u16* vp1 = vhb + (size_t)row1 * SEQ + dg * 8;
        const u16* wp0 = vlb + (size_t)row0 * SEQ + dg * 8;
        const u16* wp1 = vlb + (size_t)row1 * SEQ + dg * 8;
        rKh0 = *(const uint4*)kp0; rKh1 = *(const uint4*)kp1;
        rKl0 = *(const uint4*)lp0; rKl1 = *(const uint4*)lp1;
        rVh0 = *(const uint4*)vp0; rVh1 = *(const uint4*)vp1;
        rVl0 = *(const uint4*)wp0; rVl1 = *(const uint4*)wp1;
    }

    for (int kt = 0; kt < nt_blk; ++kt) {
        if (kt) __syncthreads();   // C: prior-tile P/V reads done before restage
        // write staged regs to LDS (compiler inserts the vmcnt wait)
        *(uint4*)((char*)Ks[0] + offs0) = rKh0;
        *(uint4*)((char*)Ks[0] + offs1) = rKh1;
        *(uint4*)((char*)Ks[1] + offs0) = rKl0;
        *(uint4*)((char*)Ks[1] + offs1) = rKl1;
        *(uint4*)((char*)Vh + offs0) = rVh0;
        *(uint4*)((char*)Vh + offs1) = rVh1;
        *(uint4*)((char*)Vl + offs0) = rVl0;
        *(uint4*)((char*)Vl + offs1) = rVl1;
        // issue next tile's loads now; they fly during QK^T/softmax/PV
        if (kt + 1 < nt_blk) {
            int kn = kt + 1;
            rKh0 = *(const uint4*)(khb + (size_t)(kn * 64 + row0) * 64 + dg * 8);
            rKh1 = *(const uint4*)(khb + (size_t)(kn * 64 + row1) * 64 + dg * 8);
            rKl0 = *(const uint4*)(klb + (size_t)(kn * 64 + row0) * 64 + dg * 8);
            rKl1 = *(const uint4*)(klb + (size_t)(kn * 64 + row1) * 64 + dg * 8);
            rVh0 = *(const uint4*)(vhb + (size_t)row0 * SEQ + kn * 64 + dg * 8);
            rVh1 = *(const uint4*)(vhb + (size_t)row1 * SEQ + kn * 64 + dg * 8);
            rVl0 = *(const uint4*)(vlb + (size_t)row0 * SEQ + kn * 64 + dg * 8);
            rVl1 = *(const uint4*)(vlb + (size_t)row1 * SEQ + kn * 64 + dg * 8);
        }
        __syncthreads();           // A: staging visible
        const bool act = (kt <= dt_w);

        f32x4_t st[4][2];
        if (act) {
            #pragma unroll
            for (int jf = 0; jf < 4; ++jf)
                #pragma unroll
                for (int nf = 0; nf < 2; ++nf)
                    st[jf][nf] = (f32x4_t){0.f, 0.f, 0.f, 0.f};
            #pragma unroll
            for (int ks = 0; ks < 2; ++ks)
                #pragma unroll
                for (int jf = 0; jf < 4; ++jf) {
                    int row = jf * 16 + rb;
                    int off = row * 128 + swz(row, ks * 64 + g * 16);
                    bf16x8_t kh8 = *(const bf16x8_t*)((char*)Ks[0] + off);
                    bf16x8_t kl8 = *(const bf16x8_t*)((char*)Ks[1] + off);
                    #pragma unroll
                    for (int nf = 0; nf < 2; ++nf) {
                        st[jf][nf] = __builtin_amdgcn_mfma_f32_16x16x32_bf16(kh8, qfh[nf][ks], st[jf][nf], 0, 0, 0);
                        st[jf][nf] = __builtin_amdgcn_mfma_f32_16x16x32_bf16(kh8, qfl[nf][ks], st[jf][nf], 0, 0, 0);
                        st[jf][nf] = __builtin_amdgcn_mfma_f32_16x16x32_bf16(kl8, qfh[nf][ks], st[jf][nf], 0, 0, 0);
                    }
                }

            if (kt == dt_w) {       // causal mask, reference semantics: -1e-9
                int mb = ((w & 1) << 5) + rb;
                #pragma unroll
                for (int jf = 0; jf < 4; ++jf)
                    #pragma unroll
                    for (int nf = 0; nf < 2; ++nf) {
                        int mm = mb + nf * 16;
                        int jb = jf * 16 + g * 4;
                        #pragma unroll
                        for (int r = 0; r < 4; ++r)
                            if (jb + r > mm) st[jf][nf][r] = -1e-9f;
                    }
            }

            float alpha[2];
            #pragma unroll
            for (int nf = 0; nf < 2; ++nf) {
                f32x4_t m4;
                #pragma unroll
                for (int r = 0; r < 4; ++r)
                    m4[r] = fmaxf(fmaxf(st[0][nf][r], st[1][nf][r]),
                                  fmaxf(st[2][nf][r], st[3][nf][r]));
                float mx = fmaxf(fmaxf(m4[0], m4[1]), fmaxf(m4[2], m4[3]));
                mx = fmaxf(mx, __shfl_xor(mx, 16));
                mx = fmaxf(mx, __shfl_xor(mx, 32));
                float nm = fmaxf(mrow[nf], mx);
                alpha[nf] = __expf(mrow[nf] - nm);
                mrow[nf] = nm;
            }
            float rsum[2] = {0.f, 0.f};
            #pragma unroll
            for (int jf = 0; jf < 4; ++jf)
                #pragma unroll
                for (int nf = 0; nf < 2; ++nf)
                    #pragma unroll
                    for (int r = 0; r < 4; ++r) {
                        float p = __expf(st[jf][nf][r] - mrow[nf]);
                        st[jf][nf][r] = p;
                        rsum[nf] += p;
                    }
            #pragma unroll
            for (int nf = 0; nf < 2; ++nf) {
                rsum[nf] += __shfl_xor(rsum[nf], 16);
                rsum[nf] += __shfl_xor(rsum[nf], 32);
                lrow[nf] = lrow[nf] * alpha[nf] + rsum[nf];
            }
            #pragma unroll
            for (int mf = 0; mf < 4; ++mf)
                #pragma unroll
                for (int nf = 0; nf < 2; ++nf)
                    #pragma unroll
                    for (int r = 0; r < 4; ++r)
                        o[mf][nf][r] *= alpha[nf];
        }

        __syncthreads();           // B: all waves' QK^T reads of K done
        if (act) {
            #pragma unroll
            for (int nf = 0; nf < 2; ++nf)
                #pragma unroll
                for (int jf = 0; jf < 4; ++jf) {
                    int m = nf * 16 + rb;
                    int off = m * 128 + swz(m, jf * 32 + g * 8);
                    ushort4 h4, l4;
                    float p0 = st[jf][nf][0], p1 = st[jf][nf][1];
                    float p2 = st[jf][nf][2], p3 = st[jf][nf][3];
                    h4.x = f2bf(p0); l4.x = f2bf(p0 - bf2f(h4.x));
                    h4.y = f2bf(p1); l4.y = f2bf(p1 - bf2f(h4.y));
                    h4.z = f2bf(p2); l4.z = f2bf(p2 - bf2f(h4.z));
                    h4.w = f2bf(p3); l4.w = f2bf(p3 - bf2f(h4.w));
                    *(ushort4*)((char*)phw + off) = h4;
                    *(ushort4*)((char*)plw + off) = l4;
                }

            #pragma unroll
            for (int kk = 0; kk < 2; ++kk) {
                bf16x8_t pbh[2], pbl[2];
                #pragma unroll
                for (int nf = 0; nf < 2; ++nf) {
                    int m = nf * 16 + rb;
                    int off = m * 128 + swz(m, kk * 64 + g * 16);
                    pbh[nf] = *(const bf16x8_t*)((char*)phw + off);
                    pbl[nf] = *(const bf16x8_t*)((char*)plw + off);
                }
                #pragma unroll
                for (int mf = 0; mf < 4; ++mf) {
                    int row = mf * 16 + rb;
                    int off = row * 128 + swz(row, kk * 64 + g * 16);
                    bf16x8_t vh8 = *(const bf16x8_t*)((char*)Vh + off);
                    bf16x8_t vl8 = *(const bf16x8_t*)((char*)Vl + off);
                    #pragma unroll
                    for (int nf = 0; nf < 2; ++nf) {
                        o[mf][nf] = __builtin_amdgcn_mfma_f32_16x16x32_bf16(vh8, pbh[nf], o[mf][nf], 0, 0, 0);
                        o[mf][nf] = __builtin_amdgcn_mfma_f32_16x16x32_bf16(vh8, pbl[nf], o[mf][nf], 0, 0, 0);
                        o[mf][nf] = __builtin_amdgcn_mfma_f32_16x16x32_bf16(vl8, pbh[nf], o[mf][nf], 0, 0, 0);
                    }
                }
            }
        }
    }

    // fully-masked suffix tiles: analytic e * suffix-colsum(V)
    const int nt_w = dt_w + 1;
    const int nfull = NKT - nt_w;
    if (nfull > 0) {
        float al2[2], ee[2];
        #pragma unroll
        for (int nf = 0; nf < 2; ++nf) {
            float mm = fmaxf(mrow[nf], -1e-9f);
            al2[nf] = __expf(mrow[nf] - mm);
            ee[nf] = __expf(-1e-9f - mm);
            lrow[nf] = lrow[nf] * al2[nf] + ee[nf] * (64.f * (float)nfull);
        }
        const float* sufp = suf + ((size_t)bh * NKT + nt_w) * 64;
        #pragma unroll
        for (int mf = 0; mf < 4; ++mf) {
            float4 sf = *(const float4*)(sufp + mf * 16 + g * 4);
            #pragma unroll
            for (int nf = 0; nf < 2; ++nf) {
                o[mf][nf][0] = o[mf][nf][0] * al2[nf] + ee[nf] * sf.x;
                o[mf][nf][1] = o[mf][nf][1] * al2[nf] + ee[nf] * sf.y;
                o[mf][nf][2] = o[mf][nf][2] * al2[nf] + ee[nf] * sf.z;
                o[mf][nf][3] = o[mf][nf][3] * al2[nf] + ee[nf] * sf.w;
            }
        }
    }

    // epilogue: normalize + write bf16 hi/lo in [B*S][DMODEL]
    float inv[2] = {1.f / lrow[0], 1.f / lrow[1]};
    #pragma unroll
    for (int mf = 0; mf < 4; ++mf)
        #pragma unroll
        for (int nf = 0; nf < 2; ++nf) {
            ushort4 h4, l4;
            float v0 = o[mf][nf][0] * inv[nf];
            float v1 = o[mf][nf][1] * inv[nf];
            float v2 = o[mf][nf][2] * inv[nf];
            float v3 = o[mf][nf][3] * inv[nf];
            h4.x = f2bf(v0); l4.x = f2bf(v0 - bf2f(h4.x));
            h4.y = f2bf(v1); l4.y = f2bf(v1 - bf2f(h4.y));
            h4.z = f2bf(v2); l4.z = f2bf(v2 - bf2f(h4.z));
            h4.w = f2bf(v3); l4.w = f2bf(v3 - bf2f(h4.w));
            size_t row = (size_t)b * SEQ + qb0 + w * 32 + nf * 16 + rb;
            size_t col = (size_t)h * 64 + mf * 16 + g * 4;
            *(ushort4*)&ahi[row * DMODEL + col] = h4;
            *(ushort4*)&alo[row * DMODEL + col] = l4;
        }
}

// ---------------------------------------------------------------------------
extern "C" void kernel_launch(void* const* d_in, const int* in_sizes, int n_in,
                              void* d_out, int out_size, void* d_ws, size_t ws_size,
                              hipStream_t stream) {
    const float* Q   = (const float*)d_in[0];
    const float* K   = (const float*)d_in[1];
    const float* V   = (const float*)d_in[2];
    // d_in[3] = mask (tril) — structure known, not read
    const float* Wq  = (const float*)d_in[4];
    const float* bq  = (const float*)d_in[5];
    const float* Wk  = (const float*)d_in[6];
    const float* bk  = (const float*)d_in[7];
    const float* Wv  = (const float*)d_in[8];
    const float* bv  = (const float*)d_in[9];
    const float* Wo  = (const float*)d_in[10];
    const float* bo  = (const float*)d_in[11];
    float* out = (float*)d_out;

    float* ws = (float*)d_ws;
    const size_t HEADSZ = (size_t)BHTOT * SEQ * HDIM;   // 4,194,304 elems
    float* cs_ws  = ws;                                  // 65536 f
    float* suf_ws = ws + 65536;                          // 65536 f
    u16* base  = (u16*)(ws + 131072);
    u16* q_hi  = base;
    u16* q_lo  = base + HEADSZ;
    u16* k_hi  = base + 2 * HEADSZ;
    u16* k_lo  = base + 3 * HEADSZ;
    u16* vt_hi = base + 4 * HEADSZ;
    u16* vt_lo = base + 5 * HEADSZ;
    u16* in_hi = base + 6 * HEADSZ;
    u16* in_lo = base + 7 * HEADSZ;
    u16* w_hi  = base + 8 * HEADSZ;
    u16* w_lo  = w_hi + (size_t)DMODEL * DMODEL;

    const int ACT_N4 = (int)(HEADSZ / 4);
    const int W_N4   = (DMODEL * DMODEL) / 4;
    dim3 sblk(256), sgrid(2048);
    dim3 gblk(256);
    dim3 ggrid(DMODEL / 128, MROWS / 128);               // 8 x 32

    // Q projection (pre-scaled by 1/8 for attention)
    split_bf16<<<sgrid, sblk, 0, stream>>>(Q, in_hi, in_lo, ACT_N4);
    split_bf16<<<dim3(1024), sblk, 0, stream>>>(Wq, w_hi, w_lo, W_N4);
    gemm_bf16_3t<3><<<ggrid, gblk, 0, stream>>>(in_hi, in_lo, w_hi, w_lo, bq, 0.125f,
                                                nullptr, q_hi, q_lo);
    // K projection
    split_bf16<<<sgrid, sblk, 0, stream>>>(K, in_hi, in_lo, ACT_N4);
    split_bf16<<<dim3(1024), sblk, 0, stream>>>(Wk, w_hi, w_lo, W_N4);
    gemm_bf16_3t<3><<<ggrid, gblk, 0, stream>>>(in_hi, in_lo, w_hi, w_lo, bk, 1.f,
                                                nullptr, k_hi, k_lo);
    // V projection (transposed head layout)
    split_bf16<<<sgrid, sblk, 0, stream>>>(V, in_hi, in_lo, ACT_N4);
    split_bf16<<<dim3(1024), sblk, 0, stream>>>(Wv, w_hi, w_lo, W_N4);
    gemm_bf16_3t<2><<<ggrid, gblk, 0, stream>>>(in_hi, in_lo, w_hi, w_lo, bv, 1.f,
                                                nullptr, vt_hi, vt_lo);

    vcolsum<<<dim3(NKT, BHTOT), dim3(64), 0, stream>>>(vt_hi, vt_lo, cs_ws);
    suffix_scan<<<dim3(BHTOT), dim3(64), 0, stream>>>(cs_ws, suf_ws);

    // MFMA flash attention -> bf16 hi/lo activations for the output GEMM
    attn_mfma<<<dim3(16 * BHTOT), gblk, 0, stream>>>(q_hi, q_lo, k_hi, k_lo,
                                                     vt_hi, vt_lo, suf_ws,
                                                     in_hi, in_lo);

    // output projection
    split_bf16<<<dim3(1024), sblk, 0, stream>>>(Wo, w_hi, w_lo, W_N4);
    gemm_bf16_3t<0><<<ggrid, gblk, 0, stream>>>(in_hi, in_lo, w_hi, w_lo, bo, 1.f,
                                                out, nullptr, nullptr);
}

// Round 13
// 301.181 us; speedup vs baseline: 1.1915x; 1.0940x over previous
//
#include <hip/hip_runtime.h>
#include <math.h>

#define SEQ 2048
#define DMODEL 1024
#define NHEADS 16
#define HDIM 64
#define BATCH 2
#define MROWS (BATCH*SEQ)    // 4096
#define BHTOT (BATCH*NHEADS) // 32
#define NKT (SEQ/64)         // 32 k-tiles per head

typedef __attribute__((ext_vector_type(8))) short bf16x8_t;
typedef __attribute__((ext_vector_type(4))) float f32x4_t;
typedef __attribute__((ext_vector_type(16))) float f32x16_t;
typedef unsigned short u16;
typedef unsigned int u32;

__device__ __forceinline__ u16 f2bf(float x) {
    u32 u = __float_as_uint(x);
    return (u16)((u + 0x7FFFu + ((u >> 16) & 1u)) >> 16);
}
__device__ __forceinline__ float bf2f(u16 h) {
    return __uint_as_float(((u32)h) << 16);
}
// XOR swizzle (T2 / m201 pattern): permute 16B slots within a 128B row
__device__ __forceinline__ int swz(int row, int colbyte) {
    return colbyte ^ ((row & 7) << 4);
}
// v_cvt_pk_bf16_f32: dst.lo16 = bf16(a), dst.hi16 = bf16(b)
__device__ __forceinline__ u32 cvtpk(float a, float b) {
    u32 r;
    asm("v_cvt_pk_bf16_f32 %0, %1, %2" : "=v"(r) : "v"(a), "v"(b));
    return r;
}
// v_permlane32_swap_b32: a.lanes[32:63] <-> b.lanes[0:31]
__device__ __forceinline__ void plswap(u32& a, u32& b) {
    asm("v_permlane32_swap_b32 %0, %1" : "+v"(a), "+v"(b));
}

// ---------------------------------------------------------------------------
// Elementwise split: x -> (hi, lo) bf16
// ---------------------------------------------------------------------------
__global__ void split_bf16(const float* __restrict__ in,
                           u16* __restrict__ hi, u16* __restrict__ lo, int n4) {
    int idx = blockIdx.x * blockDim.x + threadIdx.x;
    int stride = gridDim.x * blockDim.x;
    for (int i = idx; i < n4; i += stride) {
        float4 v = ((const float4*)in)[i];
        ushort4 h, l;
        h.x = f2bf(v.x); l.x = f2bf(v.x - bf2f(h.x));
        h.y = f2bf(v.y); l.y = f2bf(v.y - bf2f(h.y));
        h.z = f2bf(v.z); l.z = f2bf(v.z - bf2f(h.z));
        h.w = f2bf(v.w); l.w = f2bf(v.w - bf2f(h.w));
        ((ushort4*)hi)[i] = h;
        ((ushort4*)lo)[i] = l;
    }
}

// ---------------------------------------------------------------------------
// 3-term split-bf16 MFMA GEMM: C = (A @ W^T + bias) * oscale
// MODE 0: fp32 C[m*1024+n]
// MODE 2: bf16 hi/lo, V-transposed head layout [bh][64 d][2048 s]
// MODE 3: bf16 hi/lo, head layout [bh][2048 s][64 d]
// ---------------------------------------------------------------------------
template<int MODE>
__global__ __launch_bounds__(256)
void gemm_bf16_3t(const u16* __restrict__ Ahi, const u16* __restrict__ Alo,
                  const u16* __restrict__ Whi, const u16* __restrict__ Wlo,
                  const float* __restrict__ bias, float oscale,
                  float* __restrict__ C, u16* __restrict__ Ch, u16* __restrict__ Cl) {
    const int K = 1024, N = 1024;
    __shared__ u16 As_h[128 * 40];
    __shared__ u16 As_l[128 * 40];
    __shared__ u16 Ws_h[128 * 40];
    __shared__ u16 Ws_l[128 * 40];

    const int tid = threadIdx.x;
    const int lane = tid & 63, w = tid >> 6;
    const int wr = w >> 1, wc = w & 1;
    const int m0 = blockIdx.y * 128, n0 = blockIdx.x * 128;
    const int rb = lane & 15, ko = (lane >> 4) * 8;

    f32x4_t acc[4][4];
    #pragma unroll
    for (int i = 0; i < 4; ++i)
        #pragma unroll
        for (int j = 0; j < 4; ++j)
            acc[i][j] = (f32x4_t){0.f, 0.f, 0.f, 0.f};

    for (int k0 = 0; k0 < K; k0 += 32) {
        #pragma unroll
        for (int s = 0; s < 2; ++s) {
            int c = tid + s * 256;
            int r = c >> 2, q = c & 3;
            size_t ga = (size_t)(m0 + r) * K + k0 + q * 8;
            size_t gw = (size_t)(n0 + r) * K + k0 + q * 8;
            int la = r * 40 + q * 8;
            *(uint4*)&As_h[la] = *(const uint4*)&Ahi[ga];
            *(uint4*)&As_l[la] = *(const uint4*)&Alo[ga];
            *(uint4*)&Ws_h[la] = *(const uint4*)&Whi[gw];
            *(uint4*)&Ws_l[la] = *(const uint4*)&Wlo[gw];
        }
        __syncthreads();

        bf16x8_t ah[4], al[4];
        #pragma unroll
        for (int i = 0; i < 4; ++i) {
            int ra = wr * 64 + i * 16 + rb;
            ah[i] = *(const bf16x8_t*)&As_h[ra * 40 + ko];
            al[i] = *(const bf16x8_t*)&As_l[ra * 40 + ko];
        }
        #pragma unroll
        for (int j = 0; j < 4; ++j) {
            int rw = wc * 64 + j * 16 + rb;
            bf16x8_t wh = *(const bf16x8_t*)&Ws_h[rw * 40 + ko];
            bf16x8_t wl = *(const bf16x8_t*)&Ws_l[rw * 40 + ko];
            #pragma unroll
            for (int i = 0; i < 4; ++i) {
                acc[i][j] = __builtin_amdgcn_mfma_f32_16x16x32_bf16(ah[i], wh, acc[i][j], 0, 0, 0);
                acc[i][j] = __builtin_amdgcn_mfma_f32_16x16x32_bf16(ah[i], wl, acc[i][j], 0, 0, 0);
                acc[i][j] = __builtin_amdgcn_mfma_f32_16x16x32_bf16(al[i], wh, acc[i][j], 0, 0, 0);
            }
        }
        __syncthreads();
    }

    if (MODE == 2) {
        #pragma unroll
        for (int i = 0; i < 4; ++i)
            #pragma unroll
            for (int j = 0; j < 4; ++j) {
                int mb = m0 + wr * 64 + i * 16 + (lane >> 4) * 4;
                int n = n0 + wc * 64 + j * 16 + rb;
                int bb = mb >> 11, s0 = mb & (SEQ - 1);
                int hh = n >> 6, dd = n & 63;
                size_t idx = (((size_t)(bb * 16 + hh) * 64) + dd) * SEQ + s0;
                float bn = bias[n];
                ushort4 h4, l4;
                float v0 = (acc[i][j][0] + bn) * oscale;
                float v1 = (acc[i][j][1] + bn) * oscale;
                float v2 = (acc[i][j][2] + bn) * oscale;
                float v3 = (acc[i][j][3] + bn) * oscale;
                h4.x = f2bf(v0); l4.x = f2bf(v0 - bf2f(h4.x));
                h4.y = f2bf(v1); l4.y = f2bf(v1 - bf2f(h4.y));
                h4.z = f2bf(v2); l4.z = f2bf(v2 - bf2f(h4.z));
                h4.w = f2bf(v3); l4.w = f2bf(v3 - bf2f(h4.w));
                *(ushort4*)&Ch[idx] = h4;
                *(ushort4*)&Cl[idx] = l4;
            }
    } else {
        #pragma unroll
        for (int i = 0; i < 4; ++i)
            #pragma unroll
            for (int j = 0; j < 4; ++j)
                #pragma unroll
                for (int r = 0; r < 4; ++r) {
                    int m = m0 + wr * 64 + i * 16 + (lane >> 4) * 4 + r;
                    int n = n0 + wc * 64 + j * 16 + rb;
                    float v = (acc[i][j][r] + bias[n]) * oscale;
                    if (MODE == 0) {
                        C[(size_t)m * N + n] = v;
                    } else { // MODE 3
                        int bb = m >> 11, s = m & (SEQ - 1);
                        int hh = n >> 6, dd = n & 63;
                        size_t idx = (((size_t)(bb * 16 + hh) * SEQ) + s) * 64 + dd;
                        u16 t = f2bf(v);
                        Ch[idx] = t;
                        Cl[idx] = f2bf(v - bf2f(t));
                    }
                }
    }
}

// ---------------------------------------------------------------------------
// Per-tile V column sums from vT hi/lo: cs[bh][kt][d]
// ---------------------------------------------------------------------------
__global__ void vcolsum(const u16* __restrict__ vth, const u16* __restrict__ vtl,
                        float* __restrict__ cs) {
    int kt = blockIdx.x, bh = blockIdx.y, d = threadIdx.x; // 64 threads
    const u16* ph = vth + ((size_t)bh * 64 + d) * SEQ + kt * 64;
    const u16* pl = vtl + ((size_t)bh * 64 + d) * SEQ + kt * 64;
    float s = 0.f;
    #pragma unroll 16
    for (int j = 0; j < 64; ++j) s += bf2f(ph[j]) + bf2f(pl[j]);
    cs[((size_t)bh * NKT + kt) * 64 + d] = s;
}

// suffix scan: suf[bh][kt][d] = sum_{t>=kt} cs[bh][t][d]
__global__ void suffix_scan(const float* __restrict__ cs, float* __restrict__ suf) {
    int bh = blockIdx.x, d = threadIdx.x;
    float acc = 0.f;
    for (int kt = NKT - 1; kt >= 0; --kt) {
        acc += cs[((size_t)bh * NKT + kt) * 64 + d];
        suf[((size_t)bh * NKT + kt) * 64 + d] = acc;
    }
}

// ---------------------------------------------------------------------------
// MFMA flash attention on 32x32x16 frags, P entirely in registers.
// Block = 4 waves x 32 q-rows (stripe 128). S^T = mfma(K, Q): C/D col = q
// (lane-local) -> softmax needs only shfl_xor(32); P relayout to the PV
// B-operand via cvt_pk_bf16 + v_permlane32_swap. K/V in LDS (32 KB),
// XOR-swizzled; 2 barriers/tile. Fully-masked suffix handled analytically.
// q pre-scaled by 0.125 in its projection.
// ---------------------------------------------------------------------------
__global__ __launch_bounds__(256)
void attn_mfma(const u16* __restrict__ qh_g, const u16* __restrict__ ql_g,
               const u16* __restrict__ kh_g, const u16* __restrict__ kl_g,
               const u16* __restrict__ vth_g, const u16* __restrict__ vtl_g,
               const float* __restrict__ suf,
               u16* __restrict__ ahi, u16* __restrict__ alo) {
    __shared__ alignas(16) u16 Kh[4096], Kl[4096];
    __shared__ alignas(16) u16 Vh[4096], Vl[4096];   // 32 KB total

    const int tid = threadIdx.x;
    const int lane = tid & 63, w = tid >> 6;
    const int q31 = lane & 31, g2 = lane >> 5;
    const int qi = blockIdx.x >> 5;          // 0..15
    const int bh = blockIdx.x & 31;
    const int b = bh >> 4, h = bh & 15;
    const int qb0 = (15 - qi) << 7;          // heavy blocks first
    const int dt_w = (qb0 >> 6) + (w >> 1);  // this wave's diagonal tile
    const int nt_blk = (qb0 >> 6) + 2;
    const int qrow = qb0 + w * 32 + q31;     // this lane's q (global in-head)

    // Q fragments (B-operand): col=q31, k(d) = 16*ks + 8*g2 + i
    bf16x8_t qfh[4], qfl[4];
    {
        const u16* qp = qh_g + ((size_t)bh * SEQ + qrow) * 64;
        const u16* qp2 = ql_g + ((size_t)bh * SEQ + qrow) * 64;
        #pragma unroll
        for (int ks = 0; ks < 4; ++ks) {
            qfh[ks] = *(const bf16x8_t*)(qp + ks * 16 + g2 * 8);
            qfl[ks] = *(const bf16x8_t*)(qp2 + ks * 16 + g2 * 8);
        }
    }

    f32x16_t o[2];
    #pragma unroll
    for (int dt = 0; dt < 2; ++dt)
        #pragma unroll
        for (int r = 0; r < 16; ++r) o[dt][r] = 0.f;
    float mrow = -1e30f, lrow = 0.f;

    const u16* khb = kh_g + (size_t)bh * SEQ * 64;
    const u16* klb = kl_g + (size_t)bh * SEQ * 64;
    const u16* vhb = vth_g + (size_t)bh * 64 * SEQ;
    const u16* vlb = vtl_g + (size_t)bh * 64 * SEQ;

    for (int kt = 0; kt < nt_blk; ++kt) {
        if (kt) __syncthreads();   // prior-tile LDS reads done before restage
        #pragma unroll
        for (int s = 0; s < 2; ++s) {
            int gg = tid + s * 256;          // 0..511
            int row = gg >> 3, dg = gg & 7;
            int off = row * 128 + swz(row, dg * 16);
            *(uint4*)((char*)Kh + off) = *(const uint4*)(khb + (size_t)(kt * 64 + row) * 64 + dg * 8);
            *(uint4*)((char*)Kl + off) = *(const uint4*)(klb + (size_t)(kt * 64 + row) * 64 + dg * 8);
            *(uint4*)((char*)Vh + off) = *(const uint4*)(vhb + (size_t)row * SEQ + kt * 64 + dg * 8);
            *(uint4*)((char*)Vl + off) = *(const uint4*)(vlb + (size_t)row * SEQ + kt * 64 + dg * 8);
        }
        __syncthreads();           // staging visible
        if (kt > dt_w) continue;   // wave-uniform; barriers stay aligned

        // ---- QK^T: st[jt] = S^T frag (rows j, cols q) ----
        f32x16_t st[2];
        #pragma unroll
        for (int jt = 0; jt < 2; ++jt)
            #pragma unroll
            for (int r = 0; r < 16; ++r) st[jt][r] = 0.f;
        #pragma unroll
        for (int ks = 0; ks < 4; ++ks)
            #pragma unroll
            for (int jt = 0; jt < 2; ++jt) {
                int row = jt * 32 + q31;
                int off = row * 128 + swz(row, ks * 32 + g2 * 16);
                bf16x8_t kh8 = *(const bf16x8_t*)((char*)Kh + off);
                bf16x8_t kl8 = *(const bf16x8_t*)((char*)Kl + off);
                st[jt] = __builtin_amdgcn_mfma_f32_32x32x16_bf16(kh8, qfh[ks], st[jt], 0, 0, 0);
                st[jt] = __builtin_amdgcn_mfma_f32_32x32x16_bf16(kh8, qfl[ks], st[jt], 0, 0, 0);
                st[jt] = __builtin_amdgcn_mfma_f32_32x32x16_bf16(kl8, qfh[ks], st[jt], 0, 0, 0);
            }

        // causal mask on the diagonal tile (reference semantics: -1e-9)
        if (kt == dt_w) {
            #pragma unroll
            for (int jt = 0; jt < 2; ++jt)
                #pragma unroll
                for (int r = 0; r < 16; ++r) {
                    int j = kt * 64 + jt * 32 + (r & 3) + 8 * (r >> 2) + 4 * g2;
                    if (j > qrow) st[jt][r] = -1e-9f;
                }
        }

        // ---- online softmax: q is lane-local; partner lane^32 has the
        //      complementary j-subset -> one shfl_xor each for max & sum ----
        float mx = -1e30f;
        #pragma unroll
        for (int jt = 0; jt < 2; ++jt)
            #pragma unroll
            for (int r = 0; r < 16; ++r) mx = fmaxf(mx, st[jt][r]);
        mx = fmaxf(mx, __shfl_xor(mx, 32));
        float nm = fmaxf(mrow, mx);
        float alpha = __expf(mrow - nm);
        mrow = nm;
        float rs = 0.f;
        #pragma unroll
        for (int jt = 0; jt < 2; ++jt)
            #pragma unroll
            for (int r = 0; r < 16; ++r) {
                float p = __expf(st[jt][r] - nm);
                st[jt][r] = p;
                rs += p;
            }
        rs += __shfl_xor(rs, 32);
        lrow = lrow * alpha + rs;
        #pragma unroll
        for (int dt = 0; dt < 2; ++dt)
            #pragma unroll
            for (int r = 0; r < 16; ++r) o[dt][r] *= alpha;

        // ---- pack P to PV B-frags in-register (cvt_pk + permlane32_swap) ----
        bf16x8_t pbh[4], pbl[4];
        #pragma unroll
        for (int jt = 0; jt < 2; ++jt) {
            u32 hq[8], lq[8];
            #pragma unroll
            for (int p2 = 0; p2 < 8; ++p2) {
                float s0 = st[jt][p2 * 2], s1 = st[jt][p2 * 2 + 1];
                u32 hk = cvtpk(s0, s1);
                hq[p2] = hk;
                float l0 = s0 - __uint_as_float(hk << 16);
                float l1 = s1 - __uint_as_float(hk & 0xFFFF0000u);
                lq[p2] = cvtpk(l0, l1);
            }
            // halves: r0-7 -> ks=2jt, r8-15 -> ks=2jt+1
            plswap(hq[0], hq[2]); plswap(hq[1], hq[3]);
            plswap(hq[4], hq[6]); plswap(hq[5], hq[7]);
            plswap(lq[0], lq[2]); plswap(lq[1], lq[3]);
            plswap(lq[4], lq[6]); plswap(lq[5], lq[7]);
            uint4 t;
            t = (uint4){hq[0], hq[1], hq[2], hq[3]};
            pbh[2 * jt] = *(bf16x8_t*)&t;
            t = (uint4){hq[4], hq[5], hq[6], hq[7]};
            pbh[2 * jt + 1] = *(bf16x8_t*)&t;
            t = (uint4){lq[0], lq[1], lq[2], lq[3]};
            pbl[2 * jt] = *(bf16x8_t*)&t;
            t = (uint4){lq[4], lq[5], lq[6], lq[7]};
            pbl[2 * jt + 1] = *(bf16x8_t*)&t;
        }

        // ---- PV: O^T[dt] += V^T frag x P frag ----
        #pragma unroll
        for (int ks = 0; ks < 4; ++ks)
            #pragma unroll
            for (int dt = 0; dt < 2; ++dt) {
                int row = dt * 32 + q31;
                int off = row * 128 + swz(row, ks * 32 + g2 * 16);
                bf16x8_t vh8 = *(const bf16x8_t*)((char*)Vh + off);
                bf16x8_t vl8 = *(const bf16x8_t*)((char*)Vl + off);
                o[dt] = __builtin_amdgcn_mfma_f32_32x32x16_bf16(vh8, pbh[ks], o[dt], 0, 0, 0);
                o[dt] = __builtin_amdgcn_mfma_f32_32x32x16_bf16(vh8, pbl[ks], o[dt], 0, 0, 0);
                o[dt] = __builtin_amdgcn_mfma_f32_32x32x16_bf16(vl8, pbh[ks], o[dt], 0, 0, 0);
            }
    }

    // fully-masked suffix tiles: analytic e * suffix-colsum(V)
    const int nt_w = dt_w + 1;
    const int nfull = NKT - nt_w;
    if (nfull > 0) {
        float mm = fmaxf(mrow, -1e-9f);
        float al2 = __expf(mrow - mm);
        float ee = __expf(-1e-9f - mm);
        lrow = lrow * al2 + ee * (64.f * (float)nfull);
        const float* sufp = suf + ((size_t)bh * NKT + nt_w) * 64;
        #pragma unroll
        for (int dt = 0; dt < 2; ++dt)
            #pragma unroll
            for (int qq = 0; qq < 4; ++qq) {
                int d0 = dt * 32 + qq * 8 + g2 * 4;
                float4 sf = *(const float4*)(sufp + d0);
                o[dt][qq * 4 + 0] = o[dt][qq * 4 + 0] * al2 + ee * sf.x;
                o[dt][qq * 4 + 1] = o[dt][qq * 4 + 1] * al2 + ee * sf.y;
                o[dt][qq * 4 + 2] = o[dt][qq * 4 + 2] * al2 + ee * sf.z;
                o[dt][qq * 4 + 3] = o[dt][qq * 4 + 3] * al2 + ee * sf.w;
            }
    }

    // epilogue: normalize + write bf16 hi/lo in [B*S][DMODEL]
    float inv = 1.f / lrow;
    size_t rowg = (size_t)b * SEQ + qrow;
    #pragma unroll
    for (int dt = 0; dt < 2; ++dt)
        #pragma unroll
        for (int qq = 0; qq < 4; ++qq) {
            int d0 = dt * 32 + qq * 8 + g2 * 4;
            ushort4 h4, l4;
            float v0 = o[dt][qq * 4 + 0] * inv;
            float v1 = o[dt][qq * 4 + 1] * inv;
            float v2 = o[dt][qq * 4 + 2] * inv;
            float v3 = o[dt][qq * 4 + 3] * inv;
            h4.x = f2bf(v0); l4.x = f2bf(v0 - bf2f(h4.x));
            h4.y = f2bf(v1); l4.y = f2bf(v1 - bf2f(h4.y));
            h4.z = f2bf(v2); l4.z = f2bf(v2 - bf2f(h4.z));
            h4.w = f2bf(v3); l4.w = f2bf(v3 - bf2f(h4.w));
            size_t col = (size_t)h * 64 + d0;
            *(ushort4*)&ahi[rowg * DMODEL + col] = h4;
            *(ushort4*)&alo[rowg * DMODEL + col] = l4;
        }
}

// ---------------------------------------------------------------------------
extern "C" void kernel_launch(void* const* d_in, const int* in_sizes, int n_in,
                              void* d_out, int out_size, void* d_ws, size_t ws_size,
                              hipStream_t stream) {
    const float* Q   = (const float*)d_in[0];
    const float* K   = (const float*)d_in[1];
    const float* V   = (const float*)d_in[2];
    // d_in[3] = mask (tril) — structure known, not read
    const float* Wq  = (const float*)d_in[4];
    const float* bq  = (const float*)d_in[5];
    const float* Wk  = (const float*)d_in[6];
    const float* bk  = (const float*)d_in[7];
    const float* Wv  = (const float*)d_in[8];
    const float* bv  = (const float*)d_in[9];
    const float* Wo  = (const float*)d_in[10];
    const float* bo  = (const float*)d_in[11];
    float* out = (float*)d_out;

    float* ws = (float*)d_ws;
    const size_t HEADSZ = (size_t)BHTOT * SEQ * HDIM;   // 4,194,304 elems
    float* cs_ws  = ws;                                  // 65536 f
    float* suf_ws = ws + 65536;                          // 65536 f
    u16* base  = (u16*)(ws + 131072);
    u16* q_hi  = base;
    u16* q_lo  = base + HEADSZ;
    u16* k_hi  = base + 2 * HEADSZ;
    u16* k_lo  = base + 3 * HEADSZ;
    u16* vt_hi = base + 4 * HEADSZ;
    u16* vt_lo = base + 5 * HEADSZ;
    u16* in_hi = base + 6 * HEADSZ;
    u16* in_lo = base + 7 * HEADSZ;
    u16* w_hi  = base + 8 * HEADSZ;
    u16* w_lo  = w_hi + (size_t)DMODEL * DMODEL;

    const int ACT_N4 = (int)(HEADSZ / 4);
    const int W_N4   = (DMODEL * DMODEL) / 4;
    dim3 sblk(256), sgrid(2048);
    dim3 gblk(256);
    dim3 ggrid(DMODEL / 128, MROWS / 128);               // 8 x 32

    // Q projection (pre-scaled by 1/8 for attention)
    split_bf16<<<sgrid, sblk, 0, stream>>>(Q, in_hi, in_lo, ACT_N4);
    split_bf16<<<dim3(1024), sblk, 0, stream>>>(Wq, w_hi, w_lo, W_N4);
    gemm_bf16_3t<3><<<ggrid, gblk, 0, stream>>>(in_hi, in_lo, w_hi, w_lo, bq, 0.125f,
                                                nullptr, q_hi, q_lo);
    // K projection
    split_bf16<<<sgrid, sblk, 0, stream>>>(K, in_hi, in_lo, ACT_N4);
    split_bf16<<<dim3(1024), sblk, 0, stream>>>(Wk, w_hi, w_lo, W_N4);
    gemm_bf16_3t<3><<<ggrid, gblk, 0, stream>>>(in_hi, in_lo, w_hi, w_lo, bk, 1.f,
                                                nullptr, k_hi, k_lo);
    // V projection (transposed head layout)
    split_bf16<<<sgrid, sblk, 0, stream>>>(V, in_hi, in_lo, ACT_N4);
    split_bf16<<<dim3(1024), sblk, 0, stream>>>(Wv, w_hi, w_lo, W_N4);
    gemm_bf16_3t<2><<<ggrid, gblk, 0, stream>>>(in_hi, in_lo, w_hi, w_lo, bv, 1.f,
                                                nullptr, vt_hi, vt_lo);

    vcolsum<<<dim3(NKT, BHTOT), dim3(64), 0, stream>>>(vt_hi, vt_lo, cs_ws);
    suffix_scan<<<dim3(BHTOT), dim3(64), 0, stream>>>(cs_ws, suf_ws);

    // MFMA flash attention -> bf16 hi/lo activations for the output GEMM
    attn_mfma<<<dim3(16 * BHTOT), gblk, 0, stream>>>(q_hi, q_lo, k_hi, k_lo,
                                                     vt_hi, vt_lo, suf_ws,
                                                     in_hi, in_lo);

    // output projection
    split_bf16<<<dim3(1024), sblk, 0, stream>>>(Wo, w_hi, w_lo, W_N4);
    gemm_bf16_3t<0><<<ggrid, gblk, 0, stream>>>(in_hi, in_lo, w_hi, w_lo, bo, 1.f,
                                                out, nullptr, nullptr);
}

// Round 14
// 300.753 us; speedup vs baseline: 1.1932x; 1.0014x over previous
//
#include <hip/hip_runtime.h>
#include <math.h>

#define SEQ 2048
#define DMODEL 1024
#define NHEADS 16
#define HDIM 64
#define BATCH 2
#define MROWS (BATCH*SEQ)    // 4096
#define BHTOT (BATCH*NHEADS) // 32
#define NKT (SEQ/64)         // 32 k-tiles per head

typedef __attribute__((ext_vector_type(8))) short bf16x8_t;
typedef __attribute__((ext_vector_type(4))) float f32x4_t;
typedef __attribute__((ext_vector_type(16))) float f32x16_t;
typedef unsigned short u16;
typedef unsigned int u32;

__device__ __forceinline__ u16 f2bf(float x) {
    u32 u = __float_as_uint(x);
    return (u16)((u + 0x7FFFu + ((u >> 16) & 1u)) >> 16);
}
__device__ __forceinline__ float bf2f(u16 h) {
    return __uint_as_float(((u32)h) << 16);
}
// XOR swizzle (T2 / m201 pattern): permute 16B slots within a 128B row
__device__ __forceinline__ int swz(int row, int colbyte) {
    return colbyte ^ ((row & 7) << 4);
}
// v_cvt_pk_bf16_f32: dst.lo16 = bf16(a), dst.hi16 = bf16(b)
__device__ __forceinline__ u32 cvtpk(float a, float b) {
    u32 r;
    asm("v_cvt_pk_bf16_f32 %0, %1, %2" : "=v"(r) : "v"(a), "v"(b));
    return r;
}
// v_permlane32_swap_b32: a.lanes[32:63] <-> b.lanes[0:31]
__device__ __forceinline__ void plswap(u32& a, u32& b) {
    asm("v_permlane32_swap_b32 %0, %1" : "+v"(a), "+v"(b));
}

// ---------------------------------------------------------------------------
// Elementwise split: x -> (hi, lo) bf16
// ---------------------------------------------------------------------------
__global__ void split_bf16(const float* __restrict__ in,
                           u16* __restrict__ hi, u16* __restrict__ lo, int n4) {
    int idx = blockIdx.x * blockDim.x + threadIdx.x;
    int stride = gridDim.x * blockDim.x;
    for (int i = idx; i < n4; i += stride) {
        float4 v = ((const float4*)in)[i];
        ushort4 h, l;
        h.x = f2bf(v.x); l.x = f2bf(v.x - bf2f(h.x));
        h.y = f2bf(v.y); l.y = f2bf(v.y - bf2f(h.y));
        h.z = f2bf(v.z); l.z = f2bf(v.z - bf2f(h.z));
        h.w = f2bf(v.w); l.w = f2bf(v.w - bf2f(h.w));
        ((ushort4*)hi)[i] = h;
        ((ushort4*)lo)[i] = l;
    }
}

// ---------------------------------------------------------------------------
// 3-term split-bf16 MFMA GEMM: C = (A @ W^T + bias) * oscale
// MODE 0: fp32 C[m*1024+n]
// MODE 2: bf16 hi/lo, V-transposed head layout [bh][64 d][2048 s]
// MODE 3: bf16 hi/lo, head layout [bh][2048 s][64 d]
// ---------------------------------------------------------------------------
template<int MODE>
__global__ __launch_bounds__(256)
void gemm_bf16_3t(const u16* __restrict__ Ahi, const u16* __restrict__ Alo,
                  const u16* __restrict__ Whi, const u16* __restrict__ Wlo,
                  const float* __restrict__ bias, float oscale,
                  float* __restrict__ C, u16* __restrict__ Ch, u16* __restrict__ Cl) {
    const int K = 1024, N = 1024;
    __shared__ u16 As_h[128 * 40];
    __shared__ u16 As_l[128 * 40];
    __shared__ u16 Ws_h[128 * 40];
    __shared__ u16 Ws_l[128 * 40];

    const int tid = threadIdx.x;
    const int lane = tid & 63, w = tid >> 6;
    const int wr = w >> 1, wc = w & 1;
    const int m0 = blockIdx.y * 128, n0 = blockIdx.x * 128;
    const int rb = lane & 15, ko = (lane >> 4) * 8;

    f32x4_t acc[4][4];
    #pragma unroll
    for (int i = 0; i < 4; ++i)
        #pragma unroll
        for (int j = 0; j < 4; ++j)
            acc[i][j] = (f32x4_t){0.f, 0.f, 0.f, 0.f};

    for (int k0 = 0; k0 < K; k0 += 32) {
        #pragma unroll
        for (int s = 0; s < 2; ++s) {
            int c = tid + s * 256;
            int r = c >> 2, q = c & 3;
            size_t ga = (size_t)(m0 + r) * K + k0 + q * 8;
            size_t gw = (size_t)(n0 + r) * K + k0 + q * 8;
            int la = r * 40 + q * 8;
            *(uint4*)&As_h[la] = *(const uint4*)&Ahi[ga];
            *(uint4*)&As_l[la] = *(const uint4*)&Alo[ga];
            *(uint4*)&Ws_h[la] = *(const uint4*)&Whi[gw];
            *(uint4*)&Ws_l[la] = *(const uint4*)&Wlo[gw];
        }
        __syncthreads();

        bf16x8_t ah[4], al[4];
        #pragma unroll
        for (int i = 0; i < 4; ++i) {
            int ra = wr * 64 + i * 16 + rb;
            ah[i] = *(const bf16x8_t*)&As_h[ra * 40 + ko];
            al[i] = *(const bf16x8_t*)&As_l[ra * 40 + ko];
        }
        #pragma unroll
        for (int j = 0; j < 4; ++j) {
            int rw = wc * 64 + j * 16 + rb;
            bf16x8_t wh = *(const bf16x8_t*)&Ws_h[rw * 40 + ko];
            bf16x8_t wl = *(const bf16x8_t*)&Ws_l[rw * 40 + ko];
            #pragma unroll
            for (int i = 0; i < 4; ++i) {
                acc[i][j] = __builtin_amdgcn_mfma_f32_16x16x32_bf16(ah[i], wh, acc[i][j], 0, 0, 0);
                acc[i][j] = __builtin_amdgcn_mfma_f32_16x16x32_bf16(ah[i], wl, acc[i][j], 0, 0, 0);
                acc[i][j] = __builtin_amdgcn_mfma_f32_16x16x32_bf16(al[i], wh, acc[i][j], 0, 0, 0);
            }
        }
        __syncthreads();
    }

    if (MODE == 2) {
        #pragma unroll
        for (int i = 0; i < 4; ++i)
            #pragma unroll
            for (int j = 0; j < 4; ++j) {
                int mb = m0 + wr * 64 + i * 16 + (lane >> 4) * 4;
                int n = n0 + wc * 64 + j * 16 + rb;
                int bb = mb >> 11, s0 = mb & (SEQ - 1);
                int hh = n >> 6, dd = n & 63;
                size_t idx = (((size_t)(bb * 16 + hh) * 64) + dd) * SEQ + s0;
                float bn = bias[n];
                ushort4 h4, l4;
                float v0 = (acc[i][j][0] + bn) * oscale;
                float v1 = (acc[i][j][1] + bn) * oscale;
                float v2 = (acc[i][j][2] + bn) * oscale;
                float v3 = (acc[i][j][3] + bn) * oscale;
                h4.x = f2bf(v0); l4.x = f2bf(v0 - bf2f(h4.x));
                h4.y = f2bf(v1); l4.y = f2bf(v1 - bf2f(h4.y));
                h4.z = f2bf(v2); l4.z = f2bf(v2 - bf2f(h4.z));
                h4.w = f2bf(v3); l4.w = f2bf(v3 - bf2f(h4.w));
                *(ushort4*)&Ch[idx] = h4;
                *(ushort4*)&Cl[idx] = l4;
            }
    } else {
        #pragma unroll
        for (int i = 0; i < 4; ++i)
            #pragma unroll
            for (int j = 0; j < 4; ++j)
                #pragma unroll
                for (int r = 0; r < 4; ++r) {
                    int m = m0 + wr * 64 + i * 16 + (lane >> 4) * 4 + r;
                    int n = n0 + wc * 64 + j * 16 + rb;
                    float v = (acc[i][j][r] + bias[n]) * oscale;
                    if (MODE == 0) {
                        C[(size_t)m * N + n] = v;
                    } else { // MODE 3
                        int bb = m >> 11, s = m & (SEQ - 1);
                        int hh = n >> 6, dd = n & 63;
                        size_t idx = (((size_t)(bb * 16 + hh) * SEQ) + s) * 64 + dd;
                        u16 t = f2bf(v);
                        Ch[idx] = t;
                        Cl[idx] = f2bf(v - bf2f(t));
                    }
                }
    }
}

// ---------------------------------------------------------------------------
// Per-tile V column sums from vT hi/lo: cs[bh][kt][d]
// ---------------------------------------------------------------------------
__global__ void vcolsum(const u16* __restrict__ vth, const u16* __restrict__ vtl,
                        float* __restrict__ cs) {
    int kt = blockIdx.x, bh = blockIdx.y, d = threadIdx.x; // 64 threads
    const u16* ph = vth + ((size_t)bh * 64 + d) * SEQ + kt * 64;
    const u16* pl = vtl + ((size_t)bh * 64 + d) * SEQ + kt * 64;
    float s = 0.f;
    #pragma unroll 16
    for (int j = 0; j < 64; ++j) s += bf2f(ph[j]) + bf2f(pl[j]);
    cs[((size_t)bh * NKT + kt) * 64 + d] = s;
}

// suffix scan: suf[bh][kt][d] = sum_{t>=kt} cs[bh][t][d]
__global__ void suffix_scan(const float* __restrict__ cs, float* __restrict__ suf) {
    int bh = blockIdx.x, d = threadIdx.x;
    float acc = 0.f;
    for (int kt = NKT - 1; kt >= 0; --kt) {
        acc += cs[((size_t)bh * NKT + kt) * 64 + d];
        suf[((size_t)bh * NKT + kt) * 64 + d] = acc;
    }
}

// ---------------------------------------------------------------------------
// MFMA flash attention on 32x32x16 frags, P entirely in registers.
// Block = 4 waves x 32 q-rows (stripe 128). S^T = mfma(K, Q): C/D col = q
// (lane-local) -> softmax needs only shfl_xor(32); P relayout to the PV
// B-operand via cvt_pk_bf16 + v_permlane32_swap. K/V in LDS (32 KB),
// XOR-swizzled; 2 barriers/tile. Fully-masked suffix handled analytically.
// Stripe order pairs heavy+light per CU: sidx<8 -> stripe 15-sidx (round 1),
// sidx>=8 -> stripe sidx-8 (round 2); pair tile-sum = 34 = balanced.
// q pre-scaled by 0.125 in its projection.
// ---------------------------------------------------------------------------
__global__ __launch_bounds__(256)
void attn_mfma(const u16* __restrict__ qh_g, const u16* __restrict__ ql_g,
               const u16* __restrict__ kh_g, const u16* __restrict__ kl_g,
               const u16* __restrict__ vth_g, const u16* __restrict__ vtl_g,
               const float* __restrict__ suf,
               u16* __restrict__ ahi, u16* __restrict__ alo) {
    __shared__ alignas(16) u16 Kh[4096], Kl[4096];
    __shared__ alignas(16) u16 Vh[4096], Vl[4096];   // 32 KB total

    const int tid = threadIdx.x;
    const int lane = tid & 63, w = tid >> 6;
    const int q31 = lane & 31, g2 = lane >> 5;
    const int sidx = blockIdx.x >> 5;        // 0..15 dispatch slot
    const int stripe = (sidx < 8) ? (15 - sidx) : (sidx - 8);  // balanced pairing
    const int bh = blockIdx.x & 31;
    const int b = bh >> 4, h = bh & 15;
    const int qb0 = stripe << 7;
    const int dt_w = 2 * stripe + (w >> 1);  // this wave's diagonal tile
    const int nt_blk = 2 * stripe + 2;
    const int qrow = qb0 + w * 32 + q31;     // this lane's q (global in-head)

    // Q fragments (B-operand): col=q31, k(d) = 16*ks + 8*g2 + i
    bf16x8_t qfh[4], qfl[4];
    {
        const u16* qp = qh_g + ((size_t)bh * SEQ + qrow) * 64;
        const u16* qp2 = ql_g + ((size_t)bh * SEQ + qrow) * 64;
        #pragma unroll
        for (int ks = 0; ks < 4; ++ks) {
            qfh[ks] = *(const bf16x8_t*)(qp + ks * 16 + g2 * 8);
            qfl[ks] = *(const bf16x8_t*)(qp2 + ks * 16 + g2 * 8);
        }
    }

    f32x16_t o[2];
    #pragma unroll
    for (int dt = 0; dt < 2; ++dt)
        #pragma unroll
        for (int r = 0; r < 16; ++r) o[dt][r] = 0.f;
    float mrow = -1e30f, lrow = 0.f;

    const u16* khb = kh_g + (size_t)bh * SEQ * 64;
    const u16* klb = kl_g + (size_t)bh * SEQ * 64;
    const u16* vhb = vth_g + (size_t)bh * 64 * SEQ;
    const u16* vlb = vtl_g + (size_t)bh * 64 * SEQ;

    for (int kt = 0; kt < nt_blk; ++kt) {
        if (kt) __syncthreads();   // prior-tile LDS reads done before restage
        #pragma unroll
        for (int s = 0; s < 2; ++s) {
            int gg = tid + s * 256;          // 0..511
            int row = gg >> 3, dg = gg & 7;
            int off = row * 128 + swz(row, dg * 16);
            *(uint4*)((char*)Kh + off) = *(const uint4*)(khb + (size_t)(kt * 64 + row) * 64 + dg * 8);
            *(uint4*)((char*)Kl + off) = *(const uint4*)(klb + (size_t)(kt * 64 + row) * 64 + dg * 8);
            *(uint4*)((char*)Vh + off) = *(const uint4*)(vhb + (size_t)row * SEQ + kt * 64 + dg * 8);
            *(uint4*)((char*)Vl + off) = *(const uint4*)(vlb + (size_t)row * SEQ + kt * 64 + dg * 8);
        }
        __syncthreads();           // staging visible
        if (kt > dt_w) continue;   // wave-uniform; barriers stay aligned

        // ---- QK^T: st[jt] = S^T frag (rows j, cols q) ----
        f32x16_t st[2];
        #pragma unroll
        for (int jt = 0; jt < 2; ++jt)
            #pragma unroll
            for (int r = 0; r < 16; ++r) st[jt][r] = 0.f;
        #pragma unroll
        for (int ks = 0; ks < 4; ++ks)
            #pragma unroll
            for (int jt = 0; jt < 2; ++jt) {
                int row = jt * 32 + q31;
                int off = row * 128 + swz(row, ks * 32 + g2 * 16);
                bf16x8_t kh8 = *(const bf16x8_t*)((char*)Kh + off);
                bf16x8_t kl8 = *(const bf16x8_t*)((char*)Kl + off);
                st[jt] = __builtin_amdgcn_mfma_f32_32x32x16_bf16(kh8, qfh[ks], st[jt], 0, 0, 0);
                st[jt] = __builtin_amdgcn_mfma_f32_32x32x16_bf16(kh8, qfl[ks], st[jt], 0, 0, 0);
                st[jt] = __builtin_amdgcn_mfma_f32_32x32x16_bf16(kl8, qfh[ks], st[jt], 0, 0, 0);
            }

        // causal mask on the diagonal tile (reference semantics: -1e-9)
        if (kt == dt_w) {
            #pragma unroll
            for (int jt = 0; jt < 2; ++jt)
                #pragma unroll
                for (int r = 0; r < 16; ++r) {
                    int j = kt * 64 + jt * 32 + (r & 3) + 8 * (r >> 2) + 4 * g2;
                    if (j > qrow) st[jt][r] = -1e-9f;
                }
        }

        // ---- online softmax: q is lane-local; partner lane^32 has the
        //      complementary j-subset -> one shfl_xor each for max & sum ----
        float mx = -1e30f;
        #pragma unroll
        for (int jt = 0; jt < 2; ++jt)
            #pragma unroll
            for (int r = 0; r < 16; ++r) mx = fmaxf(mx, st[jt][r]);
        mx = fmaxf(mx, __shfl_xor(mx, 32));
        float nm = fmaxf(mrow, mx);
        float alpha = __expf(mrow - nm);
        mrow = nm;
        float rs = 0.f;
        #pragma unroll
        for (int jt = 0; jt < 2; ++jt)
            #pragma unroll
            for (int r = 0; r < 16; ++r) {
                float p = __expf(st[jt][r] - nm);
                st[jt][r] = p;
                rs += p;
            }
        rs += __shfl_xor(rs, 32);
        lrow = lrow * alpha + rs;
        #pragma unroll
        for (int dt = 0; dt < 2; ++dt)
            #pragma unroll
            for (int r = 0; r < 16; ++r) o[dt][r] *= alpha;

        // ---- pack P to PV B-frags in-register (cvt_pk + permlane32_swap) ----
        bf16x8_t pbh[4], pbl[4];
        #pragma unroll
        for (int jt = 0; jt < 2; ++jt) {
            u32 hq[8], lq[8];
            #pragma unroll
            for (int p2 = 0; p2 < 8; ++p2) {
                float s0 = st[jt][p2 * 2], s1 = st[jt][p2 * 2 + 1];
                u32 hk = cvtpk(s0, s1);
                hq[p2] = hk;
                float l0 = s0 - __uint_as_float(hk << 16);
                float l1 = s1 - __uint_as_float(hk & 0xFFFF0000u);
                lq[p2] = cvtpk(l0, l1);
            }
            // halves: r0-7 -> ks=2jt, r8-15 -> ks=2jt+1
            plswap(hq[0], hq[2]); plswap(hq[1], hq[3]);
            plswap(hq[4], hq[6]); plswap(hq[5], hq[7]);
            plswap(lq[0], lq[2]); plswap(lq[1], lq[3]);
            plswap(lq[4], lq[6]); plswap(lq[5], lq[7]);
            uint4 t;
            t = (uint4){hq[0], hq[1], hq[2], hq[3]};
            pbh[2 * jt] = *(bf16x8_t*)&t;
            t = (uint4){hq[4], hq[5], hq[6], hq[7]};
            pbh[2 * jt + 1] = *(bf16x8_t*)&t;
            t = (uint4){lq[0], lq[1], lq[2], lq[3]};
            pbl[2 * jt] = *(bf16x8_t*)&t;
            t = (uint4){lq[4], lq[5], lq[6], lq[7]};
            pbl[2 * jt + 1] = *(bf16x8_t*)&t;
        }

        // ---- PV: O^T[dt] += V^T frag x P frag ----
        #pragma unroll
        for (int ks = 0; ks < 4; ++ks)
            #pragma unroll
            for (int dt = 0; dt < 2; ++dt) {
                int row = dt * 32 + q31;
                int off = row * 128 + swz(row, ks * 32 + g2 * 16);
                bf16x8_t vh8 = *(const bf16x8_t*)((char*)Vh + off);
                bf16x8_t vl8 = *(const bf16x8_t*)((char*)Vl + off);
                o[dt] = __builtin_amdgcn_mfma_f32_32x32x16_bf16(vh8, pbh[ks], o[dt], 0, 0, 0);
                o[dt] = __builtin_amdgcn_mfma_f32_32x32x16_bf16(vh8, pbl[ks], o[dt], 0, 0, 0);
                o[dt] = __builtin_amdgcn_mfma_f32_32x32x16_bf16(vl8, pbh[ks], o[dt], 0, 0, 0);
            }
    }

    // fully-masked suffix tiles: analytic e * suffix-colsum(V)
    const int nt_w = dt_w + 1;
    const int nfull = NKT - nt_w;
    if (nfull > 0) {
        float mm = fmaxf(mrow, -1e-9f);
        float al2 = __expf(mrow - mm);
        float ee = __expf(-1e-9f - mm);
        lrow = lrow * al2 + ee * (64.f * (float)nfull);
        const float* sufp = suf + ((size_t)bh * NKT + nt_w) * 64;
        #pragma unroll
        for (int dt = 0; dt < 2; ++dt)
            #pragma unroll
            for (int qq = 0; qq < 4; ++qq) {
                int d0 = dt * 32 + qq * 8 + g2 * 4;
                float4 sf = *(const float4*)(sufp + d0);
                o[dt][qq * 4 + 0] = o[dt][qq * 4 + 0] * al2 + ee * sf.x;
                o[dt][qq * 4 + 1] = o[dt][qq * 4 + 1] * al2 + ee * sf.y;
                o[dt][qq * 4 + 2] = o[dt][qq * 4 + 2] * al2 + ee * sf.z;
                o[dt][qq * 4 + 3] = o[dt][qq * 4 + 3] * al2 + ee * sf.w;
            }
    }

    // epilogue: normalize + write bf16 hi/lo in [B*S][DMODEL]
    float inv = 1.f / lrow;
    size_t rowg = (size_t)b * SEQ + qrow;
    #pragma unroll
    for (int dt = 0; dt < 2; ++dt)
        #pragma unroll
        for (int qq = 0; qq < 4; ++qq) {
            int d0 = dt * 32 + qq * 8 + g2 * 4;
            ushort4 h4, l4;
            float v0 = o[dt][qq * 4 + 0] * inv;
            float v1 = o[dt][qq * 4 + 1] * inv;
            float v2 = o[dt][qq * 4 + 2] * inv;
            float v3 = o[dt][qq * 4 + 3] * inv;
            h4.x = f2bf(v0); l4.x = f2bf(v0 - bf2f(h4.x));
            h4.y = f2bf(v1); l4.y = f2bf(v1 - bf2f(h4.y));
            h4.z = f2bf(v2); l4.z = f2bf(v2 - bf2f(h4.z));
            h4.w = f2bf(v3); l4.w = f2bf(v3 - bf2f(h4.w));
            size_t col = (size_t)h * 64 + d0;
            *(ushort4*)&ahi[rowg * DMODEL + col] = h4;
            *(ushort4*)&alo[rowg * DMODEL + col] = l4;
        }
}

// ---------------------------------------------------------------------------
extern "C" void kernel_launch(void* const* d_in, const int* in_sizes, int n_in,
                              void* d_out, int out_size, void* d_ws, size_t ws_size,
                              hipStream_t stream) {
    const float* Q   = (const float*)d_in[0];
    const float* K   = (const float*)d_in[1];
    const float* V   = (const float*)d_in[2];
    // d_in[3] = mask (tril) — structure known, not read
    const float* Wq  = (const float*)d_in[4];
    const float* bq  = (const float*)d_in[5];
    const float* Wk  = (const float*)d_in[6];
    const float* bk  = (const float*)d_in[7];
    const float* Wv  = (const float*)d_in[8];
    const float* bv  = (const float*)d_in[9];
    const float* Wo  = (const float*)d_in[10];
    const float* bo  = (const float*)d_in[11];
    float* out = (float*)d_out;

    float* ws = (float*)d_ws;
    const size_t HEADSZ = (size_t)BHTOT * SEQ * HDIM;   // 4,194,304 elems
    float* cs_ws  = ws;                                  // 65536 f
    float* suf_ws = ws + 65536;                          // 65536 f
    u16* base  = (u16*)(ws + 131072);
    u16* q_hi  = base;
    u16* q_lo  = base + HEADSZ;
    u16* k_hi  = base + 2 * HEADSZ;
    u16* k_lo  = base + 3 * HEADSZ;
    u16* vt_hi = base + 4 * HEADSZ;
    u16* vt_lo = base + 5 * HEADSZ;
    u16* in_hi = base + 6 * HEADSZ;
    u16* in_lo = base + 7 * HEADSZ;
    u16* w_hi  = base + 8 * HEADSZ;
    u16* w_lo  = w_hi + (size_t)DMODEL * DMODEL;

    const int ACT_N4 = (int)(HEADSZ / 4);
    const int W_N4   = (DMODEL * DMODEL) / 4;
    dim3 sblk(256), sgrid(2048);
    dim3 gblk(256);
    dim3 ggrid(DMODEL / 128, MROWS / 128);               // 8 x 32

    // Q projection (pre-scaled by 1/8 for attention)
    split_bf16<<<sgrid, sblk, 0, stream>>>(Q, in_hi, in_lo, ACT_N4);
    split_bf16<<<dim3(1024), sblk, 0, stream>>>(Wq, w_hi, w_lo, W_N4);
    gemm_bf16_3t<3><<<ggrid, gblk, 0, stream>>>(in_hi, in_lo, w_hi, w_lo, bq, 0.125f,
                                                nullptr, q_hi, q_lo);
    // K projection
    split_bf16<<<sgrid, sblk, 0, stream>>>(K, in_hi, in_lo, ACT_N4);
    split_bf16<<<dim3(1024), sblk, 0, stream>>>(Wk, w_hi, w_lo, W_N4);
    gemm_bf16_3t<3><<<ggrid, gblk, 0, stream>>>(in_hi, in_lo, w_hi, w_lo, bk, 1.f,
                                                nullptr, k_hi, k_lo);
    // V projection (transposed head layout)
    split_bf16<<<sgrid, sblk, 0, stream>>>(V, in_hi, in_lo, ACT_N4);
    split_bf16<<<dim3(1024), sblk, 0, stream>>>(Wv, w_hi, w_lo, W_N4);
    gemm_bf16_3t<2><<<ggrid, gblk, 0, stream>>>(in_hi, in_lo, w_hi, w_lo, bv, 1.f,
                                                nullptr, vt_hi, vt_lo);

    vcolsum<<<dim3(NKT, BHTOT), dim3(64), 0, stream>>>(vt_hi, vt_lo, cs_ws);
    suffix_scan<<<dim3(BHTOT), dim3(64), 0, stream>>>(cs_ws, suf_ws);

    // MFMA flash attention -> bf16 hi/lo activations for the output GEMM
    attn_mfma<<<dim3(16 * BHTOT), gblk, 0, stream>>>(q_hi, q_lo, k_hi, k_lo,
                                                     vt_hi, vt_lo, suf_ws,
                                                     in_hi, in_lo);

    // output projection
    split_bf16<<<dim3(1024), sblk, 0, stream>>>(Wo, w_hi, w_lo, W_N4);
    gemm_bf16_3t<0><<<ggrid, gblk, 0, stream>>>(in_hi, in_lo, w_hi, w_lo, bo, 1.f,
                                                out, nullptr, nullptr);
}